// Round 1
// baseline (925.417 us; speedup 1.0000x reference)
//
#include <hip/hip_runtime.h>

// ---------------------------------------------------------------------------
// GAT pipeline, fp32 throughout.
// N=30000 nodes, E=600000 edges, IN=128, H=8, HD=32, OUT=256.
// Key choices:
//  - attention softmax without max-subtraction (logits provably bounded ~|1.5|)
//  - CSR (sorted by dst) built on-device; wave-per-node aggregation, lane owns
//    4 channels -> per-edge coalesced 1KB float4 gather of xp[src]
//  - dense GEMMs: 64x64 tile, 4x4 per thread, weights repacked transposed
//  - row-wise ops: one wave per row (256 ch = 64 lanes x float4), shfl reduce
// ---------------------------------------------------------------------------

__device__ __forceinline__ float leaky_f(float v, float s) { return v > 0.f ? v : s * v; }

// ---- repack: Wt[k][c] = W[h][k][d]  (c = h*32+d); fcT[i][o] = fc_w[o][i]; gfcT likewise
__global__ void repack_kernel(const float* __restrict__ W, const float* __restrict__ fc_w,
                              const float* __restrict__ gfc_w, float* __restrict__ Wt,
                              float* __restrict__ fcT, float* __restrict__ gfcT) {
  int i = blockIdx.x * 256 + threadIdx.x;
  if (i < 128 * 256) {
    int k = i >> 8, c = i & 255;
    Wt[i] = W[((c >> 5) * 128 + k) * 32 + (c & 31)];
  } else if (i < 128 * 256 + 256 * 256) {
    int j = i - 128 * 256;
    fcT[j] = fc_w[(j & 255) * 256 + (j >> 8)];
  } else if (i < 128 * 256 + 2 * 256 * 256) {
    int j = i - 128 * 256 - 256 * 256;
    gfcT[j] = gfc_w[(j & 255) * 256 + (j >> 8)];
  }
}

// ---- zero accumulators (ws is poisoned 0xAA before every call)
__global__ void zero_kernel(int* __restrict__ deg, float* __restrict__ xg,
                            float* __restrict__ S, int n) {
  int i = blockIdx.x * 256 + threadIdx.x;
  if (i < n) deg[i] = 0;
  if (i < 256) xg[i] = 0.f;
  if (i == 0) S[0] = 0.f;
}

// ---- generic C[n_rows,256] = act(A[n_rows,K] @ Bt[K,256] + bias)
// 64x64 tile per block, 256 threads, 4x4 acc per thread.
__global__ __launch_bounds__(256) void gemm_kernel(
    const float* __restrict__ A, const float* __restrict__ Bt,
    const float* __restrict__ bias, float* __restrict__ C,
    int n_rows, int K, int lda, float slope, int apply_act) {
  __shared__ float AsT[64][68];  // transposed A tile: AsT[k][row]
  __shared__ float Bs[64][68];   // Bs[k][col]
  int t = threadIdx.x;
  int tc = t & 15, tr = t >> 4;
  int row0 = blockIdx.x * 64, col0 = blockIdx.y * 64;
  float acc[4][4];
#pragma unroll
  for (int i = 0; i < 4; ++i)
#pragma unroll
    for (int j = 0; j < 4; ++j) acc[i][j] = 0.f;

  int arow = t >> 2;     // 0..63 (row within tile)
  int ag = t & 3;        // 0..3
  int ar = row0 + arow;
  if (ar > n_rows - 1) ar = n_rows - 1;  // clamp OOB loads, stores guarded

  for (int k0 = 0; k0 < K; k0 += 64) {
    // A tile (transposed into LDS)
#pragma unroll
    for (int j = 0; j < 4; ++j) {
      int kk = ag * 16 + j * 4;
      float4 q = *(const float4*)(A + (size_t)ar * lda + k0 + kk);
      AsT[kk + 0][arow] = q.x;
      AsT[kk + 1][arow] = q.y;
      AsT[kk + 2][arow] = q.z;
      AsT[kk + 3][arow] = q.w;
    }
    // B tile
#pragma unroll
    for (int j = 0; j < 4; ++j) {
      int kk = t >> 2;
      int cc = ag * 4 + j * 16;
      float4 q = *(const float4*)(Bt + (size_t)(k0 + kk) * 256 + col0 + cc);
      *(float4*)&Bs[kk][cc] = q;
    }
    __syncthreads();
#pragma unroll 4
    for (int kk = 0; kk < 64; ++kk) {
      float4 av = *(const float4*)&AsT[kk][tr * 4];
      float4 bv = *(const float4*)&Bs[kk][tc * 4];
      acc[0][0] += av.x * bv.x; acc[0][1] += av.x * bv.y; acc[0][2] += av.x * bv.z; acc[0][3] += av.x * bv.w;
      acc[1][0] += av.y * bv.x; acc[1][1] += av.y * bv.y; acc[1][2] += av.y * bv.z; acc[1][3] += av.y * bv.w;
      acc[2][0] += av.z * bv.x; acc[2][1] += av.z * bv.y; acc[2][2] += av.z * bv.z; acc[2][3] += av.z * bv.w;
      acc[3][0] += av.w * bv.x; acc[3][1] += av.w * bv.y; acc[3][2] += av.w * bv.z; acc[3][3] += av.w * bv.w;
    }
    __syncthreads();
  }
  float4 bb = make_float4(0.f, 0.f, 0.f, 0.f);
  if (bias) bb = *(const float4*)(bias + col0 + tc * 4);
#pragma unroll
  for (int i2 = 0; i2 < 4; ++i2) {
    int r = row0 + tr * 4 + i2;
    if (r < n_rows) {
      float4 o;
      o.x = acc[i2][0] + bb.x; o.y = acc[i2][1] + bb.y;
      o.z = acc[i2][2] + bb.z; o.w = acc[i2][3] + bb.w;
      if (apply_act) {
        o.x = leaky_f(o.x, slope); o.y = leaky_f(o.y, slope);
        o.z = leaky_f(o.z, slope); o.w = leaky_f(o.w, slope);
      }
      *(float4*)(C + (size_t)r * 256 + col0 + tc * 4) = o;
    }
  }
}

// ---- alpha_src[n,h] = xp[n,h,:].a_src[h,:]; same for dst. One thread per (n,h).
__global__ void alpha_kernel(const float4* __restrict__ xp4, const float4* __restrict__ as4,
                             const float4* __restrict__ ad4, float* __restrict__ alpha_src,
                             float* __restrict__ alpha_dst, int n_nodes) {
  int i = blockIdx.x * 256 + threadIdx.x;
  if (i >= n_nodes * 8) return;
  int n = i >> 3, h = i & 7;
  const float4* xr = xp4 + (size_t)n * 64 + h * 8;
  float s = 0.f, d = 0.f;
#pragma unroll
  for (int j = 0; j < 8; ++j) {
    float4 v = xr[j];
    float4 a = as4[h * 8 + j];
    float4 b = ad4[h * 8 + j];
    s += v.x * a.x + v.y * a.y + v.z * a.z + v.w * a.w;
    d += v.x * b.x + v.y * b.y + v.z * b.z + v.w * b.w;
  }
  alpha_src[i] = s;
  alpha_dst[i] = d;
}

// ---- CSR build
__global__ void hist_kernel(const int* __restrict__ dst, int* __restrict__ deg, int e) {
  int i = blockIdx.x * 256 + threadIdx.x;
  if (i < e) atomicAdd(&deg[dst[i]], 1);
}

__global__ __launch_bounds__(1024) void scan_kernel(const int* __restrict__ deg,
                                                    int* __restrict__ offsets, int n) {
  __shared__ int wsum[16];
  __shared__ int carry_s;
  int t = threadIdx.x, lane = t & 63, wv = t >> 6;
  if (t == 0) { carry_s = 0; offsets[0] = 0; }
  __syncthreads();
  for (int base = 0; base < n; base += 1024) {
    int i = base + t;
    int v = (i < n) ? deg[i] : 0;
    int s = v;
#pragma unroll
    for (int d = 1; d < 64; d <<= 1) {
      int u = __shfl_up(s, d);
      if (lane >= d) s += u;
    }
    if (lane == 63) wsum[wv] = s;
    __syncthreads();
    int woff = 0, total = 0;
#pragma unroll
    for (int k = 0; k < 16; ++k) {
      int wsk = wsum[k];
      woff += (k < wv) ? wsk : 0;
      total += wsk;
    }
    int carry = carry_s;
    if (i < n) offsets[i + 1] = carry + woff + s;
    __syncthreads();
    if (t == 0) carry_s = carry + total;
    __syncthreads();
  }
}

__global__ void copy_kernel(const int* __restrict__ a, int* __restrict__ b, int n) {
  int i = blockIdx.x * 256 + threadIdx.x;
  if (i < n) b[i] = a[i];
}

__global__ void scatter_kernel(const int* __restrict__ src, const int* __restrict__ dst,
                               int* __restrict__ cursor, int* __restrict__ ssrc, int e) {
  int i = blockIdx.x * 256 + threadIdx.x;
  if (i < e) {
    int p = atomicAdd(&cursor[dst[i]], 1);
    ssrc[p] = src[i];
  }
}

// ---- edge aggregation: one wave per node, lane owns 4 channels (one head per
// 8-lane group). Softmax without max-subtract (logits bounded), normalization
// folded into epilogue. Self-loop handled explicitly (not in CSR).
__global__ __launch_bounds__(256) void agg_kernel(
    const float4* __restrict__ xp4, const float* __restrict__ asrc,
    const float* __restrict__ adst, const int* __restrict__ offsets,
    const int* __restrict__ ssrc, const float4* __restrict__ conv_b4,
    float4* __restrict__ xloc4, int n_nodes) {
  int lane = threadIdx.x & 63, w = threadIdx.x >> 6;
  int n = blockIdx.x * 4 + w;
  if (n >= n_nodes) return;
  int h = lane >> 3;
  float ad = adst[n * 8 + h];
  // self loop
  float l = asrc[n * 8 + h] + ad;
  l = leaky_f(l, 0.2f);
  float p = __expf(l);
  float4 xv = xp4[(size_t)n * 64 + lane];
  float4 acc;
  acc.x = p * xv.x; acc.y = p * xv.y; acc.z = p * xv.z; acc.w = p * xv.w;
  float ssum = p;
  int beg = offsets[n], end = offsets[n + 1];
  for (int j = beg; j < end; ++j) {
    int sv = ssrc[j];
    float a1 = asrc[sv * 8 + h];
    float4 xs = xp4[(size_t)sv * 64 + lane];
    float l1 = leaky_f(a1 + ad, 0.2f);
    float p1 = __expf(l1);
    acc.x += p1 * xs.x; acc.y += p1 * xs.y; acc.z += p1 * xs.z; acc.w += p1 * xs.w;
    ssum += p1;
  }
  float inv = 1.f / (ssum + 1e-16f);
  float4 b = conv_b4[lane];
  float4 o;
  o.x = acc.x * inv + b.x; o.y = acc.y * inv + b.y;
  o.z = acc.z * inv + b.z; o.w = acc.w * inv + b.w;
  xloc4[(size_t)n * 64 + lane] = o;
}

// ---- row softmax (z1 already leaky(0.01)'d) then x2 = leaky(xloc*sa, 0.2), in-place z1
__global__ __launch_bounds__(256) void rowsm_kernel(float4* __restrict__ z1,
                                                    const float4* __restrict__ xloc,
                                                    int n_nodes) {
  int lane = threadIdx.x & 63, w = threadIdx.x >> 6;
  int n = blockIdx.x * 4 + w;
  if (n >= n_nodes) return;
  size_t idx = (size_t)n * 64 + lane;
  float4 z = z1[idx];
  float m = fmaxf(fmaxf(z.x, z.y), fmaxf(z.z, z.w));
#pragma unroll
  for (int mk = 1; mk < 64; mk <<= 1) m = fmaxf(m, __shfl_xor(m, mk));
  float4 e;
  e.x = __expf(z.x - m); e.y = __expf(z.y - m);
  e.z = __expf(z.z - m); e.w = __expf(z.w - m);
  float s = e.x + e.y + e.z + e.w;
#pragma unroll
  for (int mk = 1; mk < 64; mk <<= 1) s += __shfl_xor(s, mk);
  float inv = 1.f / s;
  float4 xv = xloc[idx];
  float4 r;
  r.x = leaky_f(xv.x * e.x * inv, 0.2f);
  r.y = leaky_f(xv.y * e.y * inv, 0.2f);
  r.z = leaky_f(xv.z * e.z * inv, 0.2f);
  r.w = leaky_f(xv.w * e.w * inv, 0.2f);
  z1[idx] = r;
}

// ---- LayerNorm + L2 normalize + gate logit, in-place. One wave per row.
__global__ __launch_bounds__(256) void ln_kernel(
    float4* __restrict__ xloc4, const float4* __restrict__ lnw4,
    const float4* __restrict__ lnb4, const float4* __restrict__ gatew4,
    const float* __restrict__ gate_b, float* __restrict__ egate,
    float* __restrict__ Ssum, int n_nodes) {
  int lane = threadIdx.x & 63, w = threadIdx.x >> 6;
  int n = blockIdx.x * 4 + w;
  if (n >= n_nodes) return;
  size_t idx = (size_t)n * 64 + lane;
  float4 v = xloc4[idx];
  float s = v.x + v.y + v.z + v.w;
#pragma unroll
  for (int mk = 1; mk < 64; mk <<= 1) s += __shfl_xor(s, mk);
  float mu = s * (1.f / 256.f);
  float4 c;
  c.x = v.x - mu; c.y = v.y - mu; c.z = v.z - mu; c.w = v.w - mu;
  float q = c.x * c.x + c.y * c.y + c.z * c.z + c.w * c.w;
#pragma unroll
  for (int mk = 1; mk < 64; mk <<= 1) q += __shfl_xor(q, mk);
  float rstd = rsqrtf(q * (1.f / 256.f) + 1e-5f);
  float4 lw = lnw4[lane], lb = lnb4[lane];
  float4 y;
  y.x = c.x * rstd * lw.x + lb.x; y.y = c.y * rstd * lw.y + lb.y;
  y.z = c.z * rstd * lw.z + lb.z; y.w = c.w * rstd * lw.w + lb.w;
  float n2 = y.x * y.x + y.y * y.y + y.z * y.z + y.w * y.w;
#pragma unroll
  for (int mk = 1; mk < 64; mk <<= 1) n2 += __shfl_xor(n2, mk);
  float inv = 1.f / fmaxf(sqrtf(n2), 1e-12f);
  y.x *= inv; y.y *= inv; y.z *= inv; y.w *= inv;
  xloc4[idx] = y;
  float4 gw = gatew4[lane];
  float gp = y.x * gw.x + y.y * gw.y + y.z * gw.z + y.w * gw.w;
#pragma unroll
  for (int mk = 1; mk < 64; mk <<= 1) gp += __shfl_xor(gp, mk);
  if (lane == 0) {
    float ev = __expf(gp + gate_b[0]);  // gate bounded: |gate| <= ||gate_w|| ~ 0.8
    egate[n] = ev;
    atomicAdd(Ssum, ev);
  }
}

// ---- pooling: xg[c] = sum_n egate[n]*x[n,c] (per-block partials + atomics)
__global__ __launch_bounds__(256) void pool_kernel(const float* __restrict__ xloc,
                                                   const float* __restrict__ egate,
                                                   float* __restrict__ xg, int n) {
  int c = threadIdx.x;
  int rpb = (n + (int)gridDim.x - 1) / (int)gridDim.x;
  int r0 = blockIdx.x * rpb;
  int r1 = r0 + rpb; if (r1 > n) r1 = n;
  float acc = 0.f;
  for (int r = r0; r < r1; ++r) acc += egate[r] * xloc[(size_t)r * 256 + c];
  atomicAdd(&xg[c], acc);
}

// ---- ga = softmax(relu((xg/S) @ gfcT + gfc_b)), one block of 256
__global__ __launch_bounds__(256) void gfc_kernel(const float* __restrict__ xg,
                                                  const float* __restrict__ S,
                                                  const float* __restrict__ gfcT,
                                                  const float* __restrict__ gfc_b,
                                                  float* __restrict__ ga) {
  __shared__ float xs[256];
  __shared__ float red[256];
  int t = threadIdx.x;
  float invS = 1.f / (S[0] + 1e-16f);
  xs[t] = xg[t] * invS;
  __syncthreads();
  float acc = gfc_b[t];
  for (int i = 0; i < 256; ++i) acc += xs[i] * gfcT[i * 256 + t];
  acc = fmaxf(acc, 0.f);
  red[t] = acc;
  __syncthreads();
  for (int s = 128; s > 0; s >>= 1) {
    if (t < s) red[t] = fmaxf(red[t], red[t + s]);
    __syncthreads();
  }
  float m = red[0];
  __syncthreads();
  float e = __expf(acc - m);
  red[t] = e;
  __syncthreads();
  for (int s = 128; s > 0; s >>= 1) {
    if (t < s) red[t] += red[t + s];
    __syncthreads();
  }
  ga[t] = e / red[0];
}

// ---- out[n,c] = x[n,c] * ga[c]
__global__ void out_kernel(const float4* __restrict__ xloc4, const float4* __restrict__ ga4,
                           float4* __restrict__ out4, int total4) {
  int i = blockIdx.x * 256 + threadIdx.x;
  if (i >= total4) return;
  float4 v = xloc4[i];
  float4 g = ga4[i & 63];
  v.x *= g.x; v.y *= g.y; v.z *= g.z; v.w *= g.w;
  out4[i] = v;
}

extern "C" void kernel_launch(void* const* d_in, const int* in_sizes, int n_in,
                              void* d_out, int out_size, void* d_ws, size_t ws_size,
                              hipStream_t stream) {
  const float* x      = (const float*)d_in[0];
  const int* edge_idx = (const int*)d_in[1];
  // d_in[2] edge_attr: unused (edge_dim=None); d_in[3] batch: all zeros, single graph
  const float* W      = (const float*)d_in[4];
  const float* a_src  = (const float*)d_in[5];
  const float* a_dst  = (const float*)d_in[6];
  const float* conv_b = (const float*)d_in[7];
  const float* fc_w   = (const float*)d_in[8];
  const float* fc_b   = (const float*)d_in[9];
  const float* ln_w   = (const float*)d_in[10];
  const float* ln_b   = (const float*)d_in[11];
  const float* gate_w = (const float*)d_in[12];
  const float* gate_b = (const float*)d_in[13];
  const float* gfc_w  = (const float*)d_in[14];
  const float* gfc_b  = (const float*)d_in[15];
  (void)n_in; (void)out_size; (void)ws_size;

  int N = in_sizes[0] / 128;
  int E = in_sizes[1] / 2;
  const int* src = edge_idx;
  const int* dst = edge_idx + E;

  char* p = (char*)d_ws;
  auto alloc = [&](size_t bytes) -> char* {
    char* r = p;
    p += (bytes + 255) & ~(size_t)255;
    return r;
  };
  float* xp    = (float*)alloc((size_t)N * 256 * 4);  // xp, later reused as z1/x2
  float* xloc  = (float*)alloc((size_t)N * 256 * 4);  // x_local, in-place updated
  float* asrc  = (float*)alloc((size_t)N * 8 * 4);
  float* adst  = (float*)alloc((size_t)N * 8 * 4);
  float* Wt    = (float*)alloc(128 * 256 * 4);
  float* fcT   = (float*)alloc(256 * 256 * 4);
  float* gfcT  = (float*)alloc(256 * 256 * 4);
  float* egate = (float*)alloc((size_t)N * 4);
  int*   deg   = (int*)alloc((size_t)N * 4);
  int*   offs  = (int*)alloc((size_t)(N + 1) * 4);
  int*   curs  = (int*)alloc((size_t)N * 4);
  int*   ssrc  = (int*)alloc((size_t)E * 4);
  float* Ssum  = (float*)alloc(256);
  float* xg    = (float*)alloc(1024);
  float* ga    = (float*)alloc(1024);

  int nb = (N + 255) / 256;
  int eb = (E + 255) / 256;
  dim3 gemm_grid((N + 63) / 64, 4);

  repack_kernel<<<(128 * 256 + 2 * 256 * 256 + 255) / 256, 256, 0, stream>>>(
      W, fc_w, gfc_w, Wt, fcT, gfcT);
  zero_kernel<<<nb, 256, 0, stream>>>(deg, xg, Ssum, N);
  // xp = x @ Wt
  gemm_kernel<<<gemm_grid, 256, 0, stream>>>(x, Wt, nullptr, xp, N, 128, 128, 0.f, 0);
  alpha_kernel<<<(N * 8 + 255) / 256, 256, 0, stream>>>(
      (const float4*)xp, (const float4*)a_src, (const float4*)a_dst, asrc, adst, N);
  // CSR build (dst-sorted src list)
  hist_kernel<<<eb, 256, 0, stream>>>(dst, deg, E);
  scan_kernel<<<1, 1024, 0, stream>>>(deg, offs, N);
  copy_kernel<<<nb, 256, 0, stream>>>(offs, curs, N);
  scatter_kernel<<<eb, 256, 0, stream>>>(src, dst, curs, ssrc, E);
  // GAT aggregation -> xloc
  agg_kernel<<<(N + 3) / 4, 256, 0, stream>>>(
      (const float4*)xp, asrc, adst, offs, ssrc, (const float4*)conv_b,
      (float4*)xloc, N);
  // dense re-attention: z1 = leaky(xloc@fcT+b, 0.01) (into xp buffer, now free)
  gemm_kernel<<<gemm_grid, 256, 0, stream>>>(xloc, fcT, fc_b, xp, N, 256, 256, 0.01f, 1);
  rowsm_kernel<<<(N + 3) / 4, 256, 0, stream>>>((float4*)xp, (const float4*)xloc, N);
  // x3 = x2@fcT+b (overwrites xloc)
  gemm_kernel<<<gemm_grid, 256, 0, stream>>>(xp, fcT, fc_b, xloc, N, 256, 256, 0.f, 0);
  // LN + L2 + gate
  ln_kernel<<<(N + 3) / 4, 256, 0, stream>>>(
      (float4*)xloc, (const float4*)ln_w, (const float4*)ln_b,
      (const float4*)gate_w, gate_b, egate, Ssum, N);
  pool_kernel<<<128, 256, 0, stream>>>(xloc, egate, xg, N);
  gfc_kernel<<<1, 256, 0, stream>>>(xg, Ssum, gfcT, gfc_b, ga);
  out_kernel<<<(N * 64 + 255) / 256, 256, 0, stream>>>(
      (const float4*)xloc, (const float4*)ga, (float4*)d_out, N * 64);
}

// Round 2
// 549.008 us; speedup vs baseline: 1.6856x; 1.6856x over previous
//
#include <hip/hip_runtime.h>

// ---------------------------------------------------------------------------
// GAT pipeline, fp32 throughout.
// N=30000 nodes, E=600000 edges, IN=128, H=8, HD=32, OUT=256.
// R1 fix: ln_kernel previously issued one atomicAdd(Ssum) PER NODE (30000
// serialized same-address atomics = 386us, 42% of runtime). Ssum is now
// reduced in pool_kernel (one atomic per block, 128 total).
// ---------------------------------------------------------------------------

__device__ __forceinline__ float leaky_f(float v, float s) { return v > 0.f ? v : s * v; }

// ---- repack: Wt[k][c] = W[h][k][d]  (c = h*32+d); fcT[i][o] = fc_w[o][i]; gfcT likewise
__global__ void repack_kernel(const float* __restrict__ W, const float* __restrict__ fc_w,
                              const float* __restrict__ gfc_w, float* __restrict__ Wt,
                              float* __restrict__ fcT, float* __restrict__ gfcT) {
  int i = blockIdx.x * 256 + threadIdx.x;
  if (i < 128 * 256) {
    int k = i >> 8, c = i & 255;
    Wt[i] = W[((c >> 5) * 128 + k) * 32 + (c & 31)];
  } else if (i < 128 * 256 + 256 * 256) {
    int j = i - 128 * 256;
    fcT[j] = fc_w[(j & 255) * 256 + (j >> 8)];
  } else if (i < 128 * 256 + 2 * 256 * 256) {
    int j = i - 128 * 256 - 256 * 256;
    gfcT[j] = gfc_w[(j & 255) * 256 + (j >> 8)];
  }
}

// ---- zero accumulators (ws is poisoned 0xAA before every call)
__global__ void zero_kernel(int* __restrict__ deg, float* __restrict__ xg,
                            float* __restrict__ S, int n) {
  int i = blockIdx.x * 256 + threadIdx.x;
  if (i < n) deg[i] = 0;
  if (i < 256) xg[i] = 0.f;
  if (i == 0) S[0] = 0.f;
}

// ---- generic C[n_rows,256] = act(A[n_rows,K] @ Bt[K,256] + bias)
// 64x64 tile per block, 256 threads, 4x4 acc per thread.
__global__ __launch_bounds__(256) void gemm_kernel(
    const float* __restrict__ A, const float* __restrict__ Bt,
    const float* __restrict__ bias, float* __restrict__ C,
    int n_rows, int K, int lda, float slope, int apply_act) {
  __shared__ float AsT[64][68];  // transposed A tile: AsT[k][row]
  __shared__ float Bs[64][68];   // Bs[k][col]
  int t = threadIdx.x;
  int tc = t & 15, tr = t >> 4;
  int row0 = blockIdx.x * 64, col0 = blockIdx.y * 64;
  float acc[4][4];
#pragma unroll
  for (int i = 0; i < 4; ++i)
#pragma unroll
    for (int j = 0; j < 4; ++j) acc[i][j] = 0.f;

  int arow = t >> 2;     // 0..63 (row within tile)
  int ag = t & 3;        // 0..3
  int ar = row0 + arow;
  if (ar > n_rows - 1) ar = n_rows - 1;  // clamp OOB loads, stores guarded

  for (int k0 = 0; k0 < K; k0 += 64) {
    // A tile (transposed into LDS)
#pragma unroll
    for (int j = 0; j < 4; ++j) {
      int kk = ag * 16 + j * 4;
      float4 q = *(const float4*)(A + (size_t)ar * lda + k0 + kk);
      AsT[kk + 0][arow] = q.x;
      AsT[kk + 1][arow] = q.y;
      AsT[kk + 2][arow] = q.z;
      AsT[kk + 3][arow] = q.w;
    }
    // B tile
#pragma unroll
    for (int j = 0; j < 4; ++j) {
      int kk = t >> 2;
      int cc = ag * 4 + j * 16;
      float4 q = *(const float4*)(Bt + (size_t)(k0 + kk) * 256 + col0 + cc);
      *(float4*)&Bs[kk][cc] = q;
    }
    __syncthreads();
#pragma unroll 4
    for (int kk = 0; kk < 64; ++kk) {
      float4 av = *(const float4*)&AsT[kk][tr * 4];
      float4 bv = *(const float4*)&Bs[kk][tc * 4];
      acc[0][0] += av.x * bv.x; acc[0][1] += av.x * bv.y; acc[0][2] += av.x * bv.z; acc[0][3] += av.x * bv.w;
      acc[1][0] += av.y * bv.x; acc[1][1] += av.y * bv.y; acc[1][2] += av.y * bv.z; acc[1][3] += av.y * bv.w;
      acc[2][0] += av.z * bv.x; acc[2][1] += av.z * bv.y; acc[2][2] += av.z * bv.z; acc[2][3] += av.z * bv.w;
      acc[3][0] += av.w * bv.x; acc[3][1] += av.w * bv.y; acc[3][2] += av.w * bv.z; acc[3][3] += av.w * bv.w;
    }
    __syncthreads();
  }
  float4 bb = make_float4(0.f, 0.f, 0.f, 0.f);
  if (bias) bb = *(const float4*)(bias + col0 + tc * 4);
#pragma unroll
  for (int i2 = 0; i2 < 4; ++i2) {
    int r = row0 + tr * 4 + i2;
    if (r < n_rows) {
      float4 o;
      o.x = acc[i2][0] + bb.x; o.y = acc[i2][1] + bb.y;
      o.z = acc[i2][2] + bb.z; o.w = acc[i2][3] + bb.w;
      if (apply_act) {
        o.x = leaky_f(o.x, slope); o.y = leaky_f(o.y, slope);
        o.z = leaky_f(o.z, slope); o.w = leaky_f(o.w, slope);
      }
      *(float4*)(C + (size_t)r * 256 + col0 + tc * 4) = o;
    }
  }
}

// ---- alpha_src[n,h] = xp[n,h,:].a_src[h,:]; same for dst. One thread per (n,h).
__global__ void alpha_kernel(const float4* __restrict__ xp4, const float4* __restrict__ as4,
                             const float4* __restrict__ ad4, float* __restrict__ alpha_src,
                             float* __restrict__ alpha_dst, int n_nodes) {
  int i = blockIdx.x * 256 + threadIdx.x;
  if (i >= n_nodes * 8) return;
  int n = i >> 3, h = i & 7;
  const float4* xr = xp4 + (size_t)n * 64 + h * 8;
  float s = 0.f, d = 0.f;
#pragma unroll
  for (int j = 0; j < 8; ++j) {
    float4 v = xr[j];
    float4 a = as4[h * 8 + j];
    float4 b = ad4[h * 8 + j];
    s += v.x * a.x + v.y * a.y + v.z * a.z + v.w * a.w;
    d += v.x * b.x + v.y * b.y + v.z * b.z + v.w * b.w;
  }
  alpha_src[i] = s;
  alpha_dst[i] = d;
}

// ---- CSR build
__global__ void hist_kernel(const int* __restrict__ dst, int* __restrict__ deg, int e) {
  int i = blockIdx.x * 256 + threadIdx.x;
  if (i < e) atomicAdd(&deg[dst[i]], 1);
}

__global__ __launch_bounds__(1024) void scan_kernel(const int* __restrict__ deg,
                                                    int* __restrict__ offsets, int n) {
  __shared__ int wsum[16];
  __shared__ int carry_s;
  int t = threadIdx.x, lane = t & 63, wv = t >> 6;
  if (t == 0) { carry_s = 0; offsets[0] = 0; }
  __syncthreads();
  for (int base = 0; base < n; base += 1024) {
    int i = base + t;
    int v = (i < n) ? deg[i] : 0;
    int s = v;
#pragma unroll
    for (int d = 1; d < 64; d <<= 1) {
      int u = __shfl_up(s, d);
      if (lane >= d) s += u;
    }
    if (lane == 63) wsum[wv] = s;
    __syncthreads();
    int woff = 0, total = 0;
#pragma unroll
    for (int k = 0; k < 16; ++k) {
      int wsk = wsum[k];
      woff += (k < wv) ? wsk : 0;
      total += wsk;
    }
    int carry = carry_s;
    if (i < n) offsets[i + 1] = carry + woff + s;
    __syncthreads();
    if (t == 0) carry_s = carry + total;
    __syncthreads();
  }
}

__global__ void copy_kernel(const int* __restrict__ a, int* __restrict__ b, int n) {
  int i = blockIdx.x * 256 + threadIdx.x;
  if (i < n) b[i] = a[i];
}

__global__ void scatter_kernel(const int* __restrict__ src, const int* __restrict__ dst,
                               int* __restrict__ cursor, int* __restrict__ ssrc, int e) {
  int i = blockIdx.x * 256 + threadIdx.x;
  if (i < e) {
    int p = atomicAdd(&cursor[dst[i]], 1);
    ssrc[p] = src[i];
  }
}

// ---- edge aggregation: one wave per node, lane owns 4 channels (one head per
// 8-lane group). Softmax without max-subtract (logits bounded), normalization
// folded into epilogue. Self-loop handled explicitly (not in CSR).
__global__ __launch_bounds__(256) void agg_kernel(
    const float4* __restrict__ xp4, const float* __restrict__ asrc,
    const float* __restrict__ adst, const int* __restrict__ offsets,
    const int* __restrict__ ssrc, const float4* __restrict__ conv_b4,
    float4* __restrict__ xloc4, int n_nodes) {
  int lane = threadIdx.x & 63, w = threadIdx.x >> 6;
  int n = blockIdx.x * 4 + w;
  if (n >= n_nodes) return;
  int h = lane >> 3;
  float ad = adst[n * 8 + h];
  // self loop
  float l = asrc[n * 8 + h] + ad;
  l = leaky_f(l, 0.2f);
  float p = __expf(l);
  float4 xv = xp4[(size_t)n * 64 + lane];
  float4 acc;
  acc.x = p * xv.x; acc.y = p * xv.y; acc.z = p * xv.z; acc.w = p * xv.w;
  float ssum = p;
  int beg = offsets[n], end = offsets[n + 1];
  for (int j = beg; j < end; ++j) {
    int sv = ssrc[j];
    float a1 = asrc[sv * 8 + h];
    float4 xs = xp4[(size_t)sv * 64 + lane];
    float l1 = leaky_f(a1 + ad, 0.2f);
    float p1 = __expf(l1);
    acc.x += p1 * xs.x; acc.y += p1 * xs.y; acc.z += p1 * xs.z; acc.w += p1 * xs.w;
    ssum += p1;
  }
  float inv = 1.f / (ssum + 1e-16f);
  float4 b = conv_b4[lane];
  float4 o;
  o.x = acc.x * inv + b.x; o.y = acc.y * inv + b.y;
  o.z = acc.z * inv + b.z; o.w = acc.w * inv + b.w;
  xloc4[(size_t)n * 64 + lane] = o;
}

// ---- row softmax (z1 already leaky(0.01)'d) then x2 = leaky(xloc*sa, 0.2), in-place z1
__global__ __launch_bounds__(256) void rowsm_kernel(float4* __restrict__ z1,
                                                    const float4* __restrict__ xloc,
                                                    int n_nodes) {
  int lane = threadIdx.x & 63, w = threadIdx.x >> 6;
  int n = blockIdx.x * 4 + w;
  if (n >= n_nodes) return;
  size_t idx = (size_t)n * 64 + lane;
  float4 z = z1[idx];
  float m = fmaxf(fmaxf(z.x, z.y), fmaxf(z.z, z.w));
#pragma unroll
  for (int mk = 1; mk < 64; mk <<= 1) m = fmaxf(m, __shfl_xor(m, mk));
  float4 e;
  e.x = __expf(z.x - m); e.y = __expf(z.y - m);
  e.z = __expf(z.z - m); e.w = __expf(z.w - m);
  float s = e.x + e.y + e.z + e.w;
#pragma unroll
  for (int mk = 1; mk < 64; mk <<= 1) s += __shfl_xor(s, mk);
  float inv = 1.f / s;
  float4 xv = xloc[idx];
  float4 r;
  r.x = leaky_f(xv.x * e.x * inv, 0.2f);
  r.y = leaky_f(xv.y * e.y * inv, 0.2f);
  r.z = leaky_f(xv.z * e.z * inv, 0.2f);
  r.w = leaky_f(xv.w * e.w * inv, 0.2f);
  z1[idx] = r;
}

// ---- LayerNorm + L2 normalize + gate logit, in-place. One wave per row.
// NOTE: no global atomics here — egate sum is reduced in pool_kernel.
__global__ __launch_bounds__(256) void ln_kernel(
    float4* __restrict__ xloc4, const float4* __restrict__ lnw4,
    const float4* __restrict__ lnb4, const float4* __restrict__ gatew4,
    const float* __restrict__ gate_b, float* __restrict__ egate, int n_nodes) {
  int lane = threadIdx.x & 63, w = threadIdx.x >> 6;
  int n = blockIdx.x * 4 + w;
  if (n >= n_nodes) return;
  size_t idx = (size_t)n * 64 + lane;
  float4 v = xloc4[idx];
  float s = v.x + v.y + v.z + v.w;
#pragma unroll
  for (int mk = 1; mk < 64; mk <<= 1) s += __shfl_xor(s, mk);
  float mu = s * (1.f / 256.f);
  float4 c;
  c.x = v.x - mu; c.y = v.y - mu; c.z = v.z - mu; c.w = v.w - mu;
  float q = c.x * c.x + c.y * c.y + c.z * c.z + c.w * c.w;
#pragma unroll
  for (int mk = 1; mk < 64; mk <<= 1) q += __shfl_xor(q, mk);
  float rstd = rsqrtf(q * (1.f / 256.f) + 1e-5f);
  float4 lw = lnw4[lane], lb = lnb4[lane];
  float4 y;
  y.x = c.x * rstd * lw.x + lb.x; y.y = c.y * rstd * lw.y + lb.y;
  y.z = c.z * rstd * lw.z + lb.z; y.w = c.w * rstd * lw.w + lb.w;
  float n2 = y.x * y.x + y.y * y.y + y.z * y.z + y.w * y.w;
#pragma unroll
  for (int mk = 1; mk < 64; mk <<= 1) n2 += __shfl_xor(n2, mk);
  float inv = 1.f / fmaxf(sqrtf(n2), 1e-12f);
  y.x *= inv; y.y *= inv; y.z *= inv; y.w *= inv;
  xloc4[idx] = y;
  float4 gw = gatew4[lane];
  float gp = y.x * gw.x + y.y * gw.y + y.z * gw.z + y.w * gw.w;
#pragma unroll
  for (int mk = 1; mk < 64; mk <<= 1) gp += __shfl_xor(gp, mk);
  if (lane == 0) {
    // gate logit bounded: |gp| <= ||gate_w|| ~ 0.8 (x is L2-normalized), exp safe
    egate[n] = __expf(gp + gate_b[0]);
  }
}

// ---- pooling: xg[c] = sum_n egate[n]*x[n,c]; also Ssum = sum_n egate[n].
// Per-block partials + one atomic per block (128 blocks).
__global__ __launch_bounds__(256) void pool_kernel(const float* __restrict__ xloc,
                                                   const float* __restrict__ egate,
                                                   float* __restrict__ xg,
                                                   float* __restrict__ Ssum, int n) {
  int c = threadIdx.x;
  int rpb = (n + (int)gridDim.x - 1) / (int)gridDim.x;
  int r0 = blockIdx.x * rpb;
  int r1 = r0 + rpb; if (r1 > n) r1 = n;
  float acc = 0.f, gs = 0.f;
  for (int r = r0; r < r1; ++r) {
    float g = egate[r];
    acc += g * xloc[(size_t)r * 256 + c];
    gs += g;
  }
  atomicAdd(&xg[c], acc);
  if (c == 0) atomicAdd(Ssum, gs);
}

// ---- ga = softmax(relu((xg/S) @ gfcT + gfc_b)), one block of 256
__global__ __launch_bounds__(256) void gfc_kernel(const float* __restrict__ xg,
                                                  const float* __restrict__ S,
                                                  const float* __restrict__ gfcT,
                                                  const float* __restrict__ gfc_b,
                                                  float* __restrict__ ga) {
  __shared__ float xs[256];
  __shared__ float red[256];
  int t = threadIdx.x;
  float invS = 1.f / (S[0] + 1e-16f);
  xs[t] = xg[t] * invS;
  __syncthreads();
  float acc = gfc_b[t];
  for (int i = 0; i < 256; ++i) acc += xs[i] * gfcT[i * 256 + t];
  acc = fmaxf(acc, 0.f);
  red[t] = acc;
  __syncthreads();
  for (int s = 128; s > 0; s >>= 1) {
    if (t < s) red[t] = fmaxf(red[t], red[t + s]);
    __syncthreads();
  }
  float m = red[0];
  __syncthreads();
  float e = __expf(acc - m);
  red[t] = e;
  __syncthreads();
  for (int s = 128; s > 0; s >>= 1) {
    if (t < s) red[t] += red[t + s];
    __syncthreads();
  }
  ga[t] = e / red[0];
}

// ---- out[n,c] = x[n,c] * ga[c]
__global__ void out_kernel(const float4* __restrict__ xloc4, const float4* __restrict__ ga4,
                           float4* __restrict__ out4, int total4) {
  int i = blockIdx.x * 256 + threadIdx.x;
  if (i >= total4) return;
  float4 v = xloc4[i];
  float4 g = ga4[i & 63];
  v.x *= g.x; v.y *= g.y; v.z *= g.z; v.w *= g.w;
  out4[i] = v;
}

extern "C" void kernel_launch(void* const* d_in, const int* in_sizes, int n_in,
                              void* d_out, int out_size, void* d_ws, size_t ws_size,
                              hipStream_t stream) {
  const float* x      = (const float*)d_in[0];
  const int* edge_idx = (const int*)d_in[1];
  // d_in[2] edge_attr: unused (edge_dim=None); d_in[3] batch: all zeros, single graph
  const float* W      = (const float*)d_in[4];
  const float* a_src  = (const float*)d_in[5];
  const float* a_dst  = (const float*)d_in[6];
  const float* conv_b = (const float*)d_in[7];
  const float* fc_w   = (const float*)d_in[8];
  const float* fc_b   = (const float*)d_in[9];
  const float* ln_w   = (const float*)d_in[10];
  const float* ln_b   = (const float*)d_in[11];
  const float* gate_w = (const float*)d_in[12];
  const float* gate_b = (const float*)d_in[13];
  const float* gfc_w  = (const float*)d_in[14];
  const float* gfc_b  = (const float*)d_in[15];
  (void)n_in; (void)out_size; (void)ws_size;

  int N = in_sizes[0] / 128;
  int E = in_sizes[1] / 2;
  const int* src = edge_idx;
  const int* dst = edge_idx + E;

  char* p = (char*)d_ws;
  auto alloc = [&](size_t bytes) -> char* {
    char* r = p;
    p += (bytes + 255) & ~(size_t)255;
    return r;
  };
  float* xp    = (float*)alloc((size_t)N * 256 * 4);  // xp, later reused as z1/x2
  float* xloc  = (float*)alloc((size_t)N * 256 * 4);  // x_local, in-place updated
  float* asrc  = (float*)alloc((size_t)N * 8 * 4);
  float* adst  = (float*)alloc((size_t)N * 8 * 4);
  float* Wt    = (float*)alloc(128 * 256 * 4);
  float* fcT   = (float*)alloc(256 * 256 * 4);
  float* gfcT  = (float*)alloc(256 * 256 * 4);
  float* egate = (float*)alloc((size_t)N * 4);
  int*   deg   = (int*)alloc((size_t)N * 4);
  int*   offs  = (int*)alloc((size_t)(N + 1) * 4);
  int*   curs  = (int*)alloc((size_t)N * 4);
  int*   ssrc  = (int*)alloc((size_t)E * 4);
  float* Ssum  = (float*)alloc(256);
  float* xg    = (float*)alloc(1024);
  float* ga    = (float*)alloc(1024);

  int nb = (N + 255) / 256;
  int eb = (E + 255) / 256;
  dim3 gemm_grid((N + 63) / 64, 4);

  repack_kernel<<<(128 * 256 + 2 * 256 * 256 + 255) / 256, 256, 0, stream>>>(
      W, fc_w, gfc_w, Wt, fcT, gfcT);
  zero_kernel<<<nb, 256, 0, stream>>>(deg, xg, Ssum, N);
  // xp = x @ Wt
  gemm_kernel<<<gemm_grid, 256, 0, stream>>>(x, Wt, nullptr, xp, N, 128, 128, 0.f, 0);
  alpha_kernel<<<(N * 8 + 255) / 256, 256, 0, stream>>>(
      (const float4*)xp, (const float4*)a_src, (const float4*)a_dst, asrc, adst, N);
  // CSR build (dst-sorted src list)
  hist_kernel<<<eb, 256, 0, stream>>>(dst, deg, E);
  scan_kernel<<<1, 1024, 0, stream>>>(deg, offs, N);
  copy_kernel<<<nb, 256, 0, stream>>>(offs, curs, N);
  scatter_kernel<<<eb, 256, 0, stream>>>(src, dst, curs, ssrc, E);
  // GAT aggregation -> xloc
  agg_kernel<<<(N + 3) / 4, 256, 0, stream>>>(
      (const float4*)xp, asrc, adst, offs, ssrc, (const float4*)conv_b,
      (float4*)xloc, N);
  // dense re-attention: z1 = leaky(xloc@fcT+b, 0.01) (into xp buffer, now free)
  gemm_kernel<<<gemm_grid, 256, 0, stream>>>(xloc, fcT, fc_b, xp, N, 256, 256, 0.01f, 1);
  rowsm_kernel<<<(N + 3) / 4, 256, 0, stream>>>((float4*)xp, (const float4*)xloc, N);
  // x3 = x2@fcT+b (overwrites xloc)
  gemm_kernel<<<gemm_grid, 256, 0, stream>>>(xp, fcT, fc_b, xloc, N, 256, 256, 0.f, 0);
  // LN + L2 + gate (no global atomics)
  ln_kernel<<<(N + 3) / 4, 256, 0, stream>>>(
      (float4*)xloc, (const float4*)ln_w, (const float4*)ln_b,
      (const float4*)gate_w, gate_b, egate, N);
  pool_kernel<<<128, 256, 0, stream>>>(xloc, egate, xg, Ssum, N);
  gfc_kernel<<<1, 256, 0, stream>>>(xg, Ssum, gfcT, gfc_b, ga);
  out_kernel<<<(N * 64 + 255) / 256, 256, 0, stream>>>(
      (const float4*)xloc, (const float4*)ga, (float4*)d_out, N * 64);
}

// Round 3
// 414.479 us; speedup vs baseline: 2.2327x; 1.3246x over previous
//
#include <hip/hip_runtime.h>

// ---------------------------------------------------------------------------
// GAT pipeline. N=30000, E=600000, IN=128, H=8, HD=32, OUT=256.
// R1: removed per-node scalar atomic (925->549us).
// R2: (a) GEMMs -> bf16 MFMA 16x16x32 (fp32 acc), 128x128 block tile;
//     (b) xp stored bf16 -> agg gather traffic halved;
//     (c) scan vectorized 4/thread.
// ---------------------------------------------------------------------------

typedef __attribute__((ext_vector_type(8))) short bf16x8;   // 8 bf16 (4 VGPRs)
typedef __attribute__((ext_vector_type(4))) float f32x4;    // MFMA acc

__device__ __forceinline__ float leaky_f(float v, float s) { return v > 0.f ? v : s * v; }
__device__ __forceinline__ unsigned short f2bf(float f) {   // RNE, no NaN expected
  unsigned int u = __float_as_uint(f);
  u += 0x7fffu + ((u >> 16) & 1u);
  return (unsigned short)(u >> 16);
}
__device__ __forceinline__ float bf2f(unsigned short u) {
  return __uint_as_float(((unsigned int)u) << 16);
}

// ---- repack: Wb[c][k]=bf16(W[h][k][d]) (c=h*32+d); fcB=bf16(fc_w) same layout
// ([o][i] == B[n][k]); gfcT fp32 transpose for the tiny gfc kernel.
__global__ void repack_kernel(const float* __restrict__ W, const float* __restrict__ fc_w,
                              const float* __restrict__ gfc_w, unsigned short* __restrict__ Wb,
                              unsigned short* __restrict__ fcB, float* __restrict__ gfcT) {
  int i = blockIdx.x * 256 + threadIdx.x;
  if (i < 256 * 128) {
    int c = i >> 7, k = i & 127;
    Wb[i] = f2bf(W[((c >> 5) * 128 + k) * 32 + (c & 31)]);
  } else if (i < 256 * 128 + 256 * 256) {
    int j = i - 256 * 128;
    fcB[j] = f2bf(fc_w[j]);
  } else if (i < 256 * 128 + 2 * 256 * 256) {
    int j = i - 256 * 128 - 256 * 256;
    gfcT[j] = gfc_w[(j & 255) * 256 + (j >> 8)];
  }
}

__global__ void zero_kernel(int* __restrict__ deg, float* __restrict__ xg,
                            float* __restrict__ S, int n) {
  int i = blockIdx.x * 256 + threadIdx.x;
  if (i < n) deg[i] = 0;
  if (i < 256) xg[i] = 0.f;
  if (i == 0) S[0] = 0.f;
}

// ---- bf16 MFMA GEMM: C[n_rows,256] = act(A[n_rows,K] @ B^T + bias)
// B given as bf16 [256][K] (n-major, k contiguous). 128x128 tile / block,
// 4 waves, each wave 64x64 = 4x4 MFMA tiles of 16x16x32. fp32 accumulate.
// A_BF16: A is bf16 [n][K]; else fp32 (converted during staging).
// OUT_BF16: write bf16, else fp32. ACT: leaky(slope).
template <int A_BF16, int OUT_BF16, int ACT>
__global__ __launch_bounds__(256) void mfma_gemm(
    const void* __restrict__ Av, const unsigned short* __restrict__ B,
    const float* __restrict__ bias, void* __restrict__ Cv,
    int n_rows, int K, float slope) {
  __shared__ short As[128][72];  // +8 bf16 pad: 144B row stride, ~2-way banks
  __shared__ short Bs[128][72];
  int t = threadIdx.x;
  int wave = t >> 6, lane = t & 63;
  int m16 = lane & 15, quad = lane >> 4;
  int row0 = blockIdx.x * 128, col0 = blockIdx.y * 128;
  int wr = (wave >> 1) * 64, wc = (wave & 1) * 64;

  f32x4 acc[4][4];
#pragma unroll
  for (int i = 0; i < 4; ++i)
#pragma unroll
    for (int j = 0; j < 4; ++j) acc[i][j] = (f32x4){0.f, 0.f, 0.f, 0.f};

  for (int k0 = 0; k0 < K; k0 += 64) {
    // ---- stage A (128 rows x 64 k)
    if (A_BF16) {
      const unsigned short* A = (const unsigned short*)Av;
#pragma unroll
      for (int p = 0; p < 4; ++p) {
        int e = (p * 256 + t) * 8;
        int row = e >> 6, k = e & 63;
        int ar = row0 + row; if (ar > n_rows - 1) ar = n_rows - 1;
        uint4 q = *(const uint4*)(A + (size_t)ar * K + k0 + k);
        *(uint4*)&As[row][k] = q;
      }
    } else {
      const float* A = (const float*)Av;
#pragma unroll
      for (int p = 0; p < 8; ++p) {
        int e = (p * 256 + t) * 4;
        int row = e >> 6, k = e & 63;
        int ar = row0 + row; if (ar > n_rows - 1) ar = n_rows - 1;
        float4 q = *(const float4*)(A + (size_t)ar * K + k0 + k);
        unsigned int lo = (unsigned int)f2bf(q.x) | ((unsigned int)f2bf(q.y) << 16);
        unsigned int hi = (unsigned int)f2bf(q.z) | ((unsigned int)f2bf(q.w) << 16);
        *(uint2*)&As[row][k] = make_uint2(lo, hi);
      }
    }
    // ---- stage B (128 cols x 64 k), already bf16 n-major
#pragma unroll
    for (int p = 0; p < 4; ++p) {
      int e = (p * 256 + t) * 8;
      int nn = e >> 6, k = e & 63;
      uint4 q = *(const uint4*)(B + (size_t)(col0 + nn) * K + k0 + k);
      *(uint4*)&Bs[nn][k] = q;
    }
    __syncthreads();
#pragma unroll
    for (int ks = 0; ks < 64; ks += 32) {
      bf16x8 af[4], bf[4];
#pragma unroll
      for (int i = 0; i < 4; ++i)
        af[i] = *(const bf16x8*)&As[wr + i * 16 + m16][ks + quad * 8];
#pragma unroll
      for (int j = 0; j < 4; ++j)
        bf[j] = *(const bf16x8*)&Bs[wc + j * 16 + m16][ks + quad * 8];
#pragma unroll
      for (int i = 0; i < 4; ++i)
#pragma unroll
        for (int j = 0; j < 4; ++j)
          acc[i][j] = __builtin_amdgcn_mfma_f32_16x16x32_bf16(af[i], bf[j], acc[i][j], 0, 0, 0);
    }
    __syncthreads();
  }
  // ---- epilogue: C/D layout col=lane&15, row=quad*4+reg
#pragma unroll
  for (int j = 0; j < 4; ++j) {
    int c = col0 + wc + j * 16 + m16;
    float bv = bias ? bias[c] : 0.f;
#pragma unroll
    for (int i = 0; i < 4; ++i) {
#pragma unroll
      for (int v = 0; v < 4; ++v) {
        int r = row0 + wr + i * 16 + quad * 4 + v;
        if (r < n_rows) {
          float val = acc[i][j][v] + bv;
          if (ACT) val = leaky_f(val, slope);
          if (OUT_BF16)
            ((unsigned short*)Cv)[(size_t)r * 256 + c] = f2bf(val);
          else
            ((float*)Cv)[(size_t)r * 256 + c] = val;
        }
      }
    }
  }
}

// ---- alpha from bf16 xp
__global__ void alpha_kernel(const unsigned short* __restrict__ xpb,
                             const float4* __restrict__ as4, const float4* __restrict__ ad4,
                             float* __restrict__ alpha_src, float* __restrict__ alpha_dst,
                             int n_nodes) {
  int i = blockIdx.x * 256 + threadIdx.x;
  if (i >= n_nodes * 8) return;
  int n = i >> 3, h = i & 7;
  const ushort4* xr = (const ushort4*)(xpb + (size_t)n * 256 + h * 32);
  float s = 0.f, d = 0.f;
#pragma unroll
  for (int j = 0; j < 8; ++j) {
    ushort4 q = xr[j];
    float4 a = as4[h * 8 + j];
    float4 b = ad4[h * 8 + j];
    float vx = bf2f(q.x), vy = bf2f(q.y), vz = bf2f(q.z), vw = bf2f(q.w);
    s += vx * a.x + vy * a.y + vz * a.z + vw * a.w;
    d += vx * b.x + vy * b.y + vz * b.z + vw * b.w;
  }
  alpha_src[i] = s;
  alpha_dst[i] = d;
}

// ---- CSR build
__global__ void hist_kernel(const int* __restrict__ dst, int* __restrict__ deg, int e) {
  int i = blockIdx.x * 256 + threadIdx.x;
  if (i < e) atomicAdd(&deg[dst[i]], 1);
}

__global__ __launch_bounds__(1024) void scan_kernel(const int* __restrict__ deg,
                                                    int* __restrict__ offsets, int n) {
  __shared__ int wsum[16];
  __shared__ int carry_s;
  int t = threadIdx.x, lane = t & 63, wv = t >> 6;
  if (t == 0) { carry_s = 0; offsets[0] = 0; }
  __syncthreads();
  for (int base = 0; base < n; base += 4096) {
    int i0 = base + t * 4;
    int4 v = make_int4(0, 0, 0, 0);
    if (i0 + 3 < n) v = *(const int4*)(deg + i0);
    else {
      if (i0 < n) v.x = deg[i0];
      if (i0 + 1 < n) v.y = deg[i0 + 1];
      if (i0 + 2 < n) v.z = deg[i0 + 2];
    }
    int p1 = v.x, p2 = p1 + v.y, p3 = p2 + v.z, p4 = p3 + v.w;
    int s = p4;
#pragma unroll
    for (int d = 1; d < 64; d <<= 1) {
      int u = __shfl_up(s, d);
      if (lane >= d) s += u;
    }
    if (lane == 63) wsum[wv] = s;
    __syncthreads();
    int woff = 0, total = 0;
#pragma unroll
    for (int k = 0; k < 16; ++k) {
      int wsk = wsum[k];
      woff += (k < wv) ? wsk : 0;
      total += wsk;
    }
    int carry = carry_s;
    int excl = carry + woff + s - p4;  // exclusive prefix before this thread's 4
    if (i0 < n) offsets[i0 + 1] = excl + p1;
    if (i0 + 1 < n) offsets[i0 + 2] = excl + p2;
    if (i0 + 2 < n) offsets[i0 + 3] = excl + p3;
    if (i0 + 3 < n) offsets[i0 + 4] = excl + p4;
    __syncthreads();
    if (t == 0) carry_s = carry + total;
    __syncthreads();
  }
}

__global__ void copy_kernel(const int* __restrict__ a, int* __restrict__ b, int n) {
  int i = blockIdx.x * 256 + threadIdx.x;
  if (i < n) b[i] = a[i];
}

__global__ void scatter_kernel(const int* __restrict__ src, const int* __restrict__ dst,
                               int* __restrict__ cursor, int* __restrict__ ssrc, int e) {
  int i = blockIdx.x * 256 + threadIdx.x;
  if (i < e) {
    int p = atomicAdd(&cursor[dst[i]], 1);
    ssrc[p] = src[i];
  }
}

// ---- edge aggregation, bf16 gather (8B/lane), fp32 accumulate.
__global__ __launch_bounds__(256) void agg_kernel(
    const unsigned short* __restrict__ xpb, const float* __restrict__ asrc,
    const float* __restrict__ adst, const int* __restrict__ offsets,
    const int* __restrict__ ssrc, const float4* __restrict__ conv_b4,
    float4* __restrict__ xloc4, int n_nodes) {
  int lane = threadIdx.x & 63, w = threadIdx.x >> 6;
  int n = blockIdx.x * 4 + w;
  if (n >= n_nodes) return;
  int h = lane >> 3;
  float ad = adst[n * 8 + h];
  float l = leaky_f(asrc[n * 8 + h] + ad, 0.2f);
  float p = __expf(l);
  ushort4 xq = ((const ushort4*)(xpb + (size_t)n * 256))[lane];
  float4 acc;
  acc.x = p * bf2f(xq.x); acc.y = p * bf2f(xq.y);
  acc.z = p * bf2f(xq.z); acc.w = p * bf2f(xq.w);
  float ssum = p;
  int beg = offsets[n], end = offsets[n + 1];
  for (int j = beg; j < end; ++j) {
    int sv = ssrc[j];
    float a1 = asrc[sv * 8 + h];
    ushort4 q = ((const ushort4*)(xpb + (size_t)sv * 256))[lane];
    float p1 = __expf(leaky_f(a1 + ad, 0.2f));
    acc.x += p1 * bf2f(q.x); acc.y += p1 * bf2f(q.y);
    acc.z += p1 * bf2f(q.z); acc.w += p1 * bf2f(q.w);
    ssum += p1;
  }
  float inv = 1.f / (ssum + 1e-16f);
  float4 b = conv_b4[lane];
  float4 o;
  o.x = acc.x * inv + b.x; o.y = acc.y * inv + b.y;
  o.z = acc.z * inv + b.z; o.w = acc.w * inv + b.w;
  xloc4[(size_t)n * 64 + lane] = o;
}

// ---- row softmax of z1 (already leaky 0.01), x2 = leaky(xloc*sa, 0.2) -> bf16
__global__ __launch_bounds__(256) void rowsm_kernel(const float4* __restrict__ z1,
                                                    const float4* __restrict__ xloc,
                                                    unsigned short* __restrict__ x2b,
                                                    int n_nodes) {
  int lane = threadIdx.x & 63, w = threadIdx.x >> 6;
  int n = blockIdx.x * 4 + w;
  if (n >= n_nodes) return;
  size_t idx = (size_t)n * 64 + lane;
  float4 z = z1[idx];
  float m = fmaxf(fmaxf(z.x, z.y), fmaxf(z.z, z.w));
#pragma unroll
  for (int mk = 1; mk < 64; mk <<= 1) m = fmaxf(m, __shfl_xor(m, mk));
  float4 e;
  e.x = __expf(z.x - m); e.y = __expf(z.y - m);
  e.z = __expf(z.z - m); e.w = __expf(z.w - m);
  float s = e.x + e.y + e.z + e.w;
#pragma unroll
  for (int mk = 1; mk < 64; mk <<= 1) s += __shfl_xor(s, mk);
  float inv = 1.f / s;
  float4 xv = xloc[idx];
  ushort4 r;
  r.x = f2bf(leaky_f(xv.x * e.x * inv, 0.2f));
  r.y = f2bf(leaky_f(xv.y * e.y * inv, 0.2f));
  r.z = f2bf(leaky_f(xv.z * e.z * inv, 0.2f));
  r.w = f2bf(leaky_f(xv.w * e.w * inv, 0.2f));
  ((ushort4*)x2b)[idx] = r;
}

// ---- LayerNorm + L2 normalize + gate logit, in-place fp32.
__global__ __launch_bounds__(256) void ln_kernel(
    float4* __restrict__ xloc4, const float4* __restrict__ lnw4,
    const float4* __restrict__ lnb4, const float4* __restrict__ gatew4,
    const float* __restrict__ gate_b, float* __restrict__ egate, int n_nodes) {
  int lane = threadIdx.x & 63, w = threadIdx.x >> 6;
  int n = blockIdx.x * 4 + w;
  if (n >= n_nodes) return;
  size_t idx = (size_t)n * 64 + lane;
  float4 v = xloc4[idx];
  float s = v.x + v.y + v.z + v.w;
#pragma unroll
  for (int mk = 1; mk < 64; mk <<= 1) s += __shfl_xor(s, mk);
  float mu = s * (1.f / 256.f);
  float4 c;
  c.x = v.x - mu; c.y = v.y - mu; c.z = v.z - mu; c.w = v.w - mu;
  float q = c.x * c.x + c.y * c.y + c.z * c.z + c.w * c.w;
#pragma unroll
  for (int mk = 1; mk < 64; mk <<= 1) q += __shfl_xor(q, mk);
  float rstd = rsqrtf(q * (1.f / 256.f) + 1e-5f);
  float4 lw = lnw4[lane], lb = lnb4[lane];
  float4 y;
  y.x = c.x * rstd * lw.x + lb.x; y.y = c.y * rstd * lw.y + lb.y;
  y.z = c.z * rstd * lw.z + lb.z; y.w = c.w * rstd * lw.w + lb.w;
  float n2 = y.x * y.x + y.y * y.y + y.z * y.z + y.w * y.w;
#pragma unroll
  for (int mk = 1; mk < 64; mk <<= 1) n2 += __shfl_xor(n2, mk);
  float inv = 1.f / fmaxf(sqrtf(n2), 1e-12f);
  y.x *= inv; y.y *= inv; y.z *= inv; y.w *= inv;
  xloc4[idx] = y;
  float4 gw = gatew4[lane];
  float gp = y.x * gw.x + y.y * gw.y + y.z * gw.z + y.w * gw.w;
#pragma unroll
  for (int mk = 1; mk < 64; mk <<= 1) gp += __shfl_xor(gp, mk);
  if (lane == 0) egate[n] = __expf(gp + gate_b[0]);  // |gp| <= ~0.8, safe
}

// ---- pooling + Ssum: per-block partials, one atomic per block
__global__ __launch_bounds__(256) void pool_kernel(const float* __restrict__ xloc,
                                                   const float* __restrict__ egate,
                                                   float* __restrict__ xg,
                                                   float* __restrict__ Ssum, int n) {
  int c = threadIdx.x;
  int rpb = (n + (int)gridDim.x - 1) / (int)gridDim.x;
  int r0 = blockIdx.x * rpb;
  int r1 = r0 + rpb; if (r1 > n) r1 = n;
  float acc = 0.f, gs = 0.f;
  for (int r = r0; r < r1; ++r) {
    float g = egate[r];
    acc += g * xloc[(size_t)r * 256 + c];
    gs += g;
  }
  atomicAdd(&xg[c], acc);
  if (c == 0) atomicAdd(Ssum, gs);
}

__global__ __launch_bounds__(256) void gfc_kernel(const float* __restrict__ xg,
                                                  const float* __restrict__ S,
                                                  const float* __restrict__ gfcT,
                                                  const float* __restrict__ gfc_b,
                                                  float* __restrict__ ga) {
  __shared__ float xs[256];
  __shared__ float red[256];
  int t = threadIdx.x;
  float invS = 1.f / (S[0] + 1e-16f);
  xs[t] = xg[t] * invS;
  __syncthreads();
  float acc = gfc_b[t];
  for (int i = 0; i < 256; ++i) acc += xs[i] * gfcT[i * 256 + t];
  acc = fmaxf(acc, 0.f);
  red[t] = acc;
  __syncthreads();
  for (int s = 128; s > 0; s >>= 1) {
    if (t < s) red[t] = fmaxf(red[t], red[t + s]);
    __syncthreads();
  }
  float m = red[0];
  __syncthreads();
  float e = __expf(acc - m);
  red[t] = e;
  __syncthreads();
  for (int s = 128; s > 0; s >>= 1) {
    if (t < s) red[t] += red[t + s];
    __syncthreads();
  }
  ga[t] = e / red[0];
}

__global__ void out_kernel(const float4* __restrict__ xloc4, const float4* __restrict__ ga4,
                           float4* __restrict__ out4, int total4) {
  int i = blockIdx.x * 256 + threadIdx.x;
  if (i >= total4) return;
  float4 v = xloc4[i];
  float4 g = ga4[i & 63];
  v.x *= g.x; v.y *= g.y; v.z *= g.z; v.w *= g.w;
  out4[i] = v;
}

extern "C" void kernel_launch(void* const* d_in, const int* in_sizes, int n_in,
                              void* d_out, int out_size, void* d_ws, size_t ws_size,
                              hipStream_t stream) {
  const float* x      = (const float*)d_in[0];
  const int* edge_idx = (const int*)d_in[1];
  const float* W      = (const float*)d_in[4];
  const float* a_src  = (const float*)d_in[5];
  const float* a_dst  = (const float*)d_in[6];
  const float* conv_b = (const float*)d_in[7];
  const float* fc_w   = (const float*)d_in[8];
  const float* fc_b   = (const float*)d_in[9];
  const float* ln_w   = (const float*)d_in[10];
  const float* ln_b   = (const float*)d_in[11];
  const float* gate_w = (const float*)d_in[12];
  const float* gate_b = (const float*)d_in[13];
  const float* gfc_w  = (const float*)d_in[14];
  const float* gfc_b  = (const float*)d_in[15];
  (void)n_in; (void)out_size; (void)ws_size;

  int N = in_sizes[0] / 128;
  int E = in_sizes[1] / 2;
  const int* src = edge_idx;
  const int* dst = edge_idx + E;

  char* p = (char*)d_ws;
  auto alloc = [&](size_t bytes) -> char* {
    char* r = p;
    p += (bytes + 255) & ~(size_t)255;
    return r;
  };
  float*          z1   = (float*)alloc((size_t)N * 256 * 4);          // gemm1 out
  float*          xloc = (float*)alloc((size_t)N * 256 * 4);          // conv out / x3 / final x
  unsigned short* xpb  = (unsigned short*)alloc((size_t)N * 256 * 2); // bf16 xp
  unsigned short* x2b  = (unsigned short*)alloc((size_t)N * 256 * 2); // bf16 x2
  float* asrc  = (float*)alloc((size_t)N * 8 * 4);
  float* adst  = (float*)alloc((size_t)N * 8 * 4);
  unsigned short* Wb   = (unsigned short*)alloc(256 * 128 * 2);
  unsigned short* fcB  = (unsigned short*)alloc(256 * 256 * 2);
  float* gfcT  = (float*)alloc(256 * 256 * 4);
  float* egate = (float*)alloc((size_t)N * 4);
  int*   deg   = (int*)alloc((size_t)N * 4);
  int*   offs  = (int*)alloc((size_t)(N + 1) * 4);
  int*   curs  = (int*)alloc((size_t)N * 4);
  int*   ssrc  = (int*)alloc((size_t)E * 4);
  float* Ssum  = (float*)alloc(256);
  float* xg    = (float*)alloc(1024);
  float* ga    = (float*)alloc(1024);

  int nb = (N + 255) / 256;
  int eb = (E + 255) / 256;
  dim3 mgrid((N + 127) / 128, 2);

  repack_kernel<<<(256 * 128 + 2 * 256 * 256 + 255) / 256, 256, 0, stream>>>(
      W, fc_w, gfc_w, Wb, fcB, gfcT);
  zero_kernel<<<nb, 256, 0, stream>>>(deg, xg, Ssum, N);
  // xp(bf16) = x @ W
  mfma_gemm<0, 1, 0><<<mgrid, 256, 0, stream>>>(x, Wb, nullptr, xpb, N, 128, 0.f);
  alpha_kernel<<<(N * 8 + 255) / 256, 256, 0, stream>>>(
      xpb, (const float4*)a_src, (const float4*)a_dst, asrc, adst, N);
  hist_kernel<<<eb, 256, 0, stream>>>(dst, deg, E);
  scan_kernel<<<1, 1024, 0, stream>>>(deg, offs, N);
  copy_kernel<<<nb, 256, 0, stream>>>(offs, curs, N);
  scatter_kernel<<<eb, 256, 0, stream>>>(src, dst, curs, ssrc, E);
  agg_kernel<<<(N + 3) / 4, 256, 0, stream>>>(
      xpb, asrc, adst, offs, ssrc, (const float4*)conv_b, (float4*)xloc, N);
  // z1 = leaky(xloc@fc^T + b, 0.01)
  mfma_gemm<0, 0, 1><<<mgrid, 256, 0, stream>>>(xloc, fcB, fc_b, z1, N, 256, 0.01f);
  rowsm_kernel<<<(N + 3) / 4, 256, 0, stream>>>(
      (const float4*)z1, (const float4*)xloc, x2b, N);
  // x3 = x2@fc^T + b  (overwrites xloc)
  mfma_gemm<1, 0, 0><<<mgrid, 256, 0, stream>>>(x2b, fcB, fc_b, xloc, N, 256, 0.f);
  ln_kernel<<<(N + 3) / 4, 256, 0, stream>>>(
      (float4*)xloc, (const float4*)ln_w, (const float4*)ln_b,
      (const float4*)gate_w, gate_b, egate, N);
  pool_kernel<<<128, 256, 0, stream>>>(xloc, egate, xg, Ssum, N);
  gfc_kernel<<<1, 256, 0, stream>>>(xg, Ssum, gfcT, gfc_b, ga);
  out_kernel<<<(N * 64 + 255) / 256, 256, 0, stream>>>(
      (const float4*)xloc, (const float4*)ga, (float4*)d_out, N * 64);
}

// Round 4
// 389.734 us; speedup vs baseline: 2.3745x; 1.0635x over previous
//
#include <hip/hip_runtime.h>

// ---------------------------------------------------------------------------
// GAT pipeline. N=30000, E=600000, IN=128, H=8, HD=32, OUT=256.
// R1: removed per-node scalar atomic (925->549us).
// R2: bf16 MFMA GEMMs + bf16 gather (549->414us).
// R3: agg edge-loop software-pipelined x4 (was latency-bound: serial
//     ssrc->gather dependent chain, 28% HBM / 31% VALU); scan writes curs
//     (copy_kernel dispatch removed).
// ---------------------------------------------------------------------------

typedef __attribute__((ext_vector_type(8))) short bf16x8;   // 8 bf16 (4 VGPRs)
typedef __attribute__((ext_vector_type(4))) float f32x4;    // MFMA acc

__device__ __forceinline__ float leaky_f(float v, float s) { return v > 0.f ? v : s * v; }
__device__ __forceinline__ unsigned short f2bf(float f) {   // RNE, no NaN expected
  unsigned int u = __float_as_uint(f);
  u += 0x7fffu + ((u >> 16) & 1u);
  return (unsigned short)(u >> 16);
}
__device__ __forceinline__ float bf2f(unsigned short u) {
  return __uint_as_float(((unsigned int)u) << 16);
}

// ---- repack: Wb[c][k]=bf16(W[h][k][d]) (c=h*32+d); fcB=bf16(fc_w) same layout
// ([o][i] == B[n][k]); gfcT fp32 transpose for the tiny gfc kernel.
__global__ void repack_kernel(const float* __restrict__ W, const float* __restrict__ fc_w,
                              const float* __restrict__ gfc_w, unsigned short* __restrict__ Wb,
                              unsigned short* __restrict__ fcB, float* __restrict__ gfcT) {
  int i = blockIdx.x * 256 + threadIdx.x;
  if (i < 256 * 128) {
    int c = i >> 7, k = i & 127;
    Wb[i] = f2bf(W[((c >> 5) * 128 + k) * 32 + (c & 31)]);
  } else if (i < 256 * 128 + 256 * 256) {
    int j = i - 256 * 128;
    fcB[j] = f2bf(fc_w[j]);
  } else if (i < 256 * 128 + 2 * 256 * 256) {
    int j = i - 256 * 128 - 256 * 256;
    gfcT[j] = gfc_w[(j & 255) * 256 + (j >> 8)];
  }
}

__global__ void zero_kernel(int* __restrict__ deg, float* __restrict__ xg,
                            float* __restrict__ S, int n) {
  int i = blockIdx.x * 256 + threadIdx.x;
  if (i < n) deg[i] = 0;
  if (i < 256) xg[i] = 0.f;
  if (i == 0) S[0] = 0.f;
}

// ---- bf16 MFMA GEMM: C[n_rows,256] = act(A[n_rows,K] @ B^T + bias)
// B given as bf16 [256][K] (n-major, k contiguous). 128x128 tile / block,
// 4 waves, each wave 64x64 = 4x4 MFMA tiles of 16x16x32. fp32 accumulate.
template <int A_BF16, int OUT_BF16, int ACT>
__global__ __launch_bounds__(256) void mfma_gemm(
    const void* __restrict__ Av, const unsigned short* __restrict__ B,
    const float* __restrict__ bias, void* __restrict__ Cv,
    int n_rows, int K, float slope) {
  __shared__ short As[128][72];  // +8 bf16 pad: 144B row stride, ~2-way banks
  __shared__ short Bs[128][72];
  int t = threadIdx.x;
  int wave = t >> 6, lane = t & 63;
  int m16 = lane & 15, quad = lane >> 4;
  int row0 = blockIdx.x * 128, col0 = blockIdx.y * 128;
  int wr = (wave >> 1) * 64, wc = (wave & 1) * 64;

  f32x4 acc[4][4];
#pragma unroll
  for (int i = 0; i < 4; ++i)
#pragma unroll
    for (int j = 0; j < 4; ++j) acc[i][j] = (f32x4){0.f, 0.f, 0.f, 0.f};

  for (int k0 = 0; k0 < K; k0 += 64) {
    if (A_BF16) {
      const unsigned short* A = (const unsigned short*)Av;
#pragma unroll
      for (int p = 0; p < 4; ++p) {
        int e = (p * 256 + t) * 8;
        int row = e >> 6, k = e & 63;
        int ar = row0 + row; if (ar > n_rows - 1) ar = n_rows - 1;
        uint4 q = *(const uint4*)(A + (size_t)ar * K + k0 + k);
        *(uint4*)&As[row][k] = q;
      }
    } else {
      const float* A = (const float*)Av;
#pragma unroll
      for (int p = 0; p < 8; ++p) {
        int e = (p * 256 + t) * 4;
        int row = e >> 6, k = e & 63;
        int ar = row0 + row; if (ar > n_rows - 1) ar = n_rows - 1;
        float4 q = *(const float4*)(A + (size_t)ar * K + k0 + k);
        unsigned int lo = (unsigned int)f2bf(q.x) | ((unsigned int)f2bf(q.y) << 16);
        unsigned int hi = (unsigned int)f2bf(q.z) | ((unsigned int)f2bf(q.w) << 16);
        *(uint2*)&As[row][k] = make_uint2(lo, hi);
      }
    }
#pragma unroll
    for (int p = 0; p < 4; ++p) {
      int e = (p * 256 + t) * 8;
      int nn = e >> 6, k = e & 63;
      uint4 q = *(const uint4*)(B + (size_t)(col0 + nn) * K + k0 + k);
      *(uint4*)&Bs[nn][k] = q;
    }
    __syncthreads();
#pragma unroll
    for (int ks = 0; ks < 64; ks += 32) {
      bf16x8 af[4], bf[4];
#pragma unroll
      for (int i = 0; i < 4; ++i)
        af[i] = *(const bf16x8*)&As[wr + i * 16 + m16][ks + quad * 8];
#pragma unroll
      for (int j = 0; j < 4; ++j)
        bf[j] = *(const bf16x8*)&Bs[wc + j * 16 + m16][ks + quad * 8];
#pragma unroll
      for (int i = 0; i < 4; ++i)
#pragma unroll
        for (int j = 0; j < 4; ++j)
          acc[i][j] = __builtin_amdgcn_mfma_f32_16x16x32_bf16(af[i], bf[j], acc[i][j], 0, 0, 0);
    }
    __syncthreads();
  }
  // ---- epilogue: C/D layout col=lane&15, row=quad*4+reg
#pragma unroll
  for (int j = 0; j < 4; ++j) {
    int c = col0 + wc + j * 16 + m16;
    float bv = bias ? bias[c] : 0.f;
#pragma unroll
    for (int i = 0; i < 4; ++i) {
#pragma unroll
      for (int v = 0; v < 4; ++v) {
        int r = row0 + wr + i * 16 + quad * 4 + v;
        if (r < n_rows) {
          float val = acc[i][j][v] + bv;
          if (ACT) val = leaky_f(val, slope);
          if (OUT_BF16)
            ((unsigned short*)Cv)[(size_t)r * 256 + c] = f2bf(val);
          else
            ((float*)Cv)[(size_t)r * 256 + c] = val;
        }
      }
    }
  }
}

// ---- alpha from bf16 xp
__global__ void alpha_kernel(const unsigned short* __restrict__ xpb,
                             const float4* __restrict__ as4, const float4* __restrict__ ad4,
                             float* __restrict__ alpha_src, float* __restrict__ alpha_dst,
                             int n_nodes) {
  int i = blockIdx.x * 256 + threadIdx.x;
  if (i >= n_nodes * 8) return;
  int n = i >> 3, h = i & 7;
  const ushort4* xr = (const ushort4*)(xpb + (size_t)n * 256 + h * 32);
  float s = 0.f, d = 0.f;
#pragma unroll
  for (int j = 0; j < 8; ++j) {
    ushort4 q = xr[j];
    float4 a = as4[h * 8 + j];
    float4 b = ad4[h * 8 + j];
    float vx = bf2f(q.x), vy = bf2f(q.y), vz = bf2f(q.z), vw = bf2f(q.w);
    s += vx * a.x + vy * a.y + vz * a.z + vw * a.w;
    d += vx * b.x + vy * b.y + vz * b.z + vw * b.w;
  }
  alpha_src[i] = s;
  alpha_dst[i] = d;
}

// ---- CSR build
__global__ void hist_kernel(const int* __restrict__ dst, int* __restrict__ deg, int e) {
  int i = blockIdx.x * 256 + threadIdx.x;
  if (i < e) atomicAdd(&deg[dst[i]], 1);
}

// scan also emits curs[i] = offsets[i] (exclusive prefix), saving a copy pass
__global__ __launch_bounds__(1024) void scan_kernel(const int* __restrict__ deg,
                                                    int* __restrict__ offsets,
                                                    int* __restrict__ curs, int n) {
  __shared__ int wsum[16];
  __shared__ int carry_s;
  int t = threadIdx.x, lane = t & 63, wv = t >> 6;
  if (t == 0) { carry_s = 0; offsets[0] = 0; }
  __syncthreads();
  for (int base = 0; base < n; base += 4096) {
    int i0 = base + t * 4;
    int4 v = make_int4(0, 0, 0, 0);
    if (i0 + 3 < n) v = *(const int4*)(deg + i0);
    else {
      if (i0 < n) v.x = deg[i0];
      if (i0 + 1 < n) v.y = deg[i0 + 1];
      if (i0 + 2 < n) v.z = deg[i0 + 2];
    }
    int p1 = v.x, p2 = p1 + v.y, p3 = p2 + v.z, p4 = p3 + v.w;
    int s = p4;
#pragma unroll
    for (int d = 1; d < 64; d <<= 1) {
      int u = __shfl_up(s, d);
      if (lane >= d) s += u;
    }
    if (lane == 63) wsum[wv] = s;
    __syncthreads();
    int woff = 0, total = 0;
#pragma unroll
    for (int k = 0; k < 16; ++k) {
      int wsk = wsum[k];
      woff += (k < wv) ? wsk : 0;
      total += wsk;
    }
    int carry = carry_s;
    int excl = carry + woff + s - p4;  // exclusive prefix before this thread's 4
    if (i0 < n)     { offsets[i0 + 1] = excl + p1; curs[i0]     = excl; }
    if (i0 + 1 < n) { offsets[i0 + 2] = excl + p2; curs[i0 + 1] = excl + p1; }
    if (i0 + 2 < n) { offsets[i0 + 3] = excl + p3; curs[i0 + 2] = excl + p2; }
    if (i0 + 3 < n) { offsets[i0 + 4] = excl + p4; curs[i0 + 3] = excl + p3; }
    __syncthreads();
    if (t == 0) carry_s = carry + total;
    __syncthreads();
  }
}

__global__ void scatter_kernel(const int* __restrict__ src, const int* __restrict__ dst,
                               int* __restrict__ cursor, int* __restrict__ ssrc, int e) {
  int i = blockIdx.x * 256 + threadIdx.x;
  if (i < e) {
    int p = atomicAdd(&cursor[dst[i]], 1);
    ssrc[p] = src[i];
  }
}

// ---- edge aggregation, bf16 gather, fp32 accumulate. Edge loop unrolled x4:
// 4 independent index loads + 4 independent 512B gathers in flight per wave
// (was a serial load->gather->fma chain: latency-bound at 28% HBM).
__global__ __launch_bounds__(256) void agg_kernel(
    const unsigned short* __restrict__ xpb, const float* __restrict__ asrc,
    const float* __restrict__ adst, const int* __restrict__ offsets,
    const int* __restrict__ ssrc, const float4* __restrict__ conv_b4,
    float4* __restrict__ xloc4, int n_nodes) {
  int lane = threadIdx.x & 63, w = threadIdx.x >> 6;
  int n = blockIdx.x * 4 + w;
  if (n >= n_nodes) return;
  int h = lane >> 3;
  float ad = adst[n * 8 + h];
  float p = __expf(leaky_f(asrc[n * 8 + h] + ad, 0.2f));
  ushort4 xq = ((const ushort4*)(xpb + (size_t)n * 256))[lane];
  float4 acc;
  acc.x = p * bf2f(xq.x); acc.y = p * bf2f(xq.y);
  acc.z = p * bf2f(xq.z); acc.w = p * bf2f(xq.w);
  float ssum = p;
  int beg = offsets[n], end = offsets[n + 1];
  int j = beg;
  for (; j + 4 <= end; j += 4) {
    int sv0 = ssrc[j], sv1 = ssrc[j + 1], sv2 = ssrc[j + 2], sv3 = ssrc[j + 3];
    float a0 = asrc[sv0 * 8 + h];
    float a1 = asrc[sv1 * 8 + h];
    float a2 = asrc[sv2 * 8 + h];
    float a3 = asrc[sv3 * 8 + h];
    ushort4 q0 = ((const ushort4*)(xpb + (size_t)sv0 * 256))[lane];
    ushort4 q1 = ((const ushort4*)(xpb + (size_t)sv1 * 256))[lane];
    ushort4 q2 = ((const ushort4*)(xpb + (size_t)sv2 * 256))[lane];
    ushort4 q3 = ((const ushort4*)(xpb + (size_t)sv3 * 256))[lane];
    float p0 = __expf(leaky_f(a0 + ad, 0.2f));
    float p1 = __expf(leaky_f(a1 + ad, 0.2f));
    float p2 = __expf(leaky_f(a2 + ad, 0.2f));
    float p3 = __expf(leaky_f(a3 + ad, 0.2f));
    acc.x += p0 * bf2f(q0.x); acc.y += p0 * bf2f(q0.y);
    acc.z += p0 * bf2f(q0.z); acc.w += p0 * bf2f(q0.w);
    acc.x += p1 * bf2f(q1.x); acc.y += p1 * bf2f(q1.y);
    acc.z += p1 * bf2f(q1.z); acc.w += p1 * bf2f(q1.w);
    acc.x += p2 * bf2f(q2.x); acc.y += p2 * bf2f(q2.y);
    acc.z += p2 * bf2f(q2.z); acc.w += p2 * bf2f(q2.w);
    acc.x += p3 * bf2f(q3.x); acc.y += p3 * bf2f(q3.y);
    acc.z += p3 * bf2f(q3.z); acc.w += p3 * bf2f(q3.w);
    ssum += p0 + p1 + p2 + p3;
  }
  for (; j < end; ++j) {
    int sv = ssrc[j];
    float a1 = asrc[sv * 8 + h];
    ushort4 q = ((const ushort4*)(xpb + (size_t)sv * 256))[lane];
    float p1 = __expf(leaky_f(a1 + ad, 0.2f));
    acc.x += p1 * bf2f(q.x); acc.y += p1 * bf2f(q.y);
    acc.z += p1 * bf2f(q.z); acc.w += p1 * bf2f(q.w);
    ssum += p1;
  }
  float inv = 1.f / (ssum + 1e-16f);
  float4 b = conv_b4[lane];
  float4 o;
  o.x = acc.x * inv + b.x; o.y = acc.y * inv + b.y;
  o.z = acc.z * inv + b.z; o.w = acc.w * inv + b.w;
  xloc4[(size_t)n * 64 + lane] = o;
}

// ---- row softmax of z1 (already leaky 0.01), x2 = leaky(xloc*sa, 0.2) -> bf16
__global__ __launch_bounds__(256) void rowsm_kernel(const float4* __restrict__ z1,
                                                    const float4* __restrict__ xloc,
                                                    unsigned short* __restrict__ x2b,
                                                    int n_nodes) {
  int lane = threadIdx.x & 63, w = threadIdx.x >> 6;
  int n = blockIdx.x * 4 + w;
  if (n >= n_nodes) return;
  size_t idx = (size_t)n * 64 + lane;
  float4 z = z1[idx];
  float m = fmaxf(fmaxf(z.x, z.y), fmaxf(z.z, z.w));
#pragma unroll
  for (int mk = 1; mk < 64; mk <<= 1) m = fmaxf(m, __shfl_xor(m, mk));
  float4 e;
  e.x = __expf(z.x - m); e.y = __expf(z.y - m);
  e.z = __expf(z.z - m); e.w = __expf(z.w - m);
  float s = e.x + e.y + e.z + e.w;
#pragma unroll
  for (int mk = 1; mk < 64; mk <<= 1) s += __shfl_xor(s, mk);
  float inv = 1.f / s;
  float4 xv = xloc[idx];
  ushort4 r;
  r.x = f2bf(leaky_f(xv.x * e.x * inv, 0.2f));
  r.y = f2bf(leaky_f(xv.y * e.y * inv, 0.2f));
  r.z = f2bf(leaky_f(xv.z * e.z * inv, 0.2f));
  r.w = f2bf(leaky_f(xv.w * e.w * inv, 0.2f));
  ((ushort4*)x2b)[idx] = r;
}

// ---- LayerNorm + L2 normalize + gate logit, in-place fp32.
__global__ __launch_bounds__(256) void ln_kernel(
    float4* __restrict__ xloc4, const float4* __restrict__ lnw4,
    const float4* __restrict__ lnb4, const float4* __restrict__ gatew4,
    const float* __restrict__ gate_b, float* __restrict__ egate, int n_nodes) {
  int lane = threadIdx.x & 63, w = threadIdx.x >> 6;
  int n = blockIdx.x * 4 + w;
  if (n >= n_nodes) return;
  size_t idx = (size_t)n * 64 + lane;
  float4 v = xloc4[idx];
  float s = v.x + v.y + v.z + v.w;
#pragma unroll
  for (int mk = 1; mk < 64; mk <<= 1) s += __shfl_xor(s, mk);
  float mu = s * (1.f / 256.f);
  float4 c;
  c.x = v.x - mu; c.y = v.y - mu; c.z = v.z - mu; c.w = v.w - mu;
  float q = c.x * c.x + c.y * c.y + c.z * c.z + c.w * c.w;
#pragma unroll
  for (int mk = 1; mk < 64; mk <<= 1) q += __shfl_xor(q, mk);
  float rstd = rsqrtf(q * (1.f / 256.f) + 1e-5f);
  float4 lw = lnw4[lane], lb = lnb4[lane];
  float4 y;
  y.x = c.x * rstd * lw.x + lb.x; y.y = c.y * rstd * lw.y + lb.y;
  y.z = c.z * rstd * lw.z + lb.z; y.w = c.w * rstd * lw.w + lb.w;
  float n2 = y.x * y.x + y.y * y.y + y.z * y.z + y.w * y.w;
#pragma unroll
  for (int mk = 1; mk < 64; mk <<= 1) n2 += __shfl_xor(n2, mk);
  float inv = 1.f / fmaxf(sqrtf(n2), 1e-12f);
  y.x *= inv; y.y *= inv; y.z *= inv; y.w *= inv;
  xloc4[idx] = y;
  float4 gw = gatew4[lane];
  float gp = y.x * gw.x + y.y * gw.y + y.z * gw.z + y.w * gw.w;
#pragma unroll
  for (int mk = 1; mk < 64; mk <<= 1) gp += __shfl_xor(gp, mk);
  if (lane == 0) egate[n] = __expf(gp + gate_b[0]);  // |gp| <= ~0.8, safe
}

// ---- pooling + Ssum: per-block partials, one atomic per block
__global__ __launch_bounds__(256) void pool_kernel(const float* __restrict__ xloc,
                                                   const float* __restrict__ egate,
                                                   float* __restrict__ xg,
                                                   float* __restrict__ Ssum, int n) {
  int c = threadIdx.x;
  int rpb = (n + (int)gridDim.x - 1) / (int)gridDim.x;
  int r0 = blockIdx.x * rpb;
  int r1 = r0 + rpb; if (r1 > n) r1 = n;
  float acc = 0.f, gs = 0.f;
  for (int r = r0; r < r1; ++r) {
    float g = egate[r];
    acc += g * xloc[(size_t)r * 256 + c];
    gs += g;
  }
  atomicAdd(&xg[c], acc);
  if (c == 0) atomicAdd(Ssum, gs);
}

__global__ __launch_bounds__(256) void gfc_kernel(const float* __restrict__ xg,
                                                  const float* __restrict__ S,
                                                  const float* __restrict__ gfcT,
                                                  const float* __restrict__ gfc_b,
                                                  float* __restrict__ ga) {
  __shared__ float xs[256];
  __shared__ float red[256];
  int t = threadIdx.x;
  float invS = 1.f / (S[0] + 1e-16f);
  xs[t] = xg[t] * invS;
  __syncthreads();
  float acc = gfc_b[t];
  for (int i = 0; i < 256; ++i) acc += xs[i] * gfcT[i * 256 + t];
  acc = fmaxf(acc, 0.f);
  red[t] = acc;
  __syncthreads();
  for (int s = 128; s > 0; s >>= 1) {
    if (t < s) red[t] = fmaxf(red[t], red[t + s]);
    __syncthreads();
  }
  float m = red[0];
  __syncthreads();
  float e = __expf(acc - m);
  red[t] = e;
  __syncthreads();
  for (int s = 128; s > 0; s >>= 1) {
    if (t < s) red[t] += red[t + s];
    __syncthreads();
  }
  ga[t] = e / red[0];
}

__global__ void out_kernel(const float4* __restrict__ xloc4, const float4* __restrict__ ga4,
                           float4* __restrict__ out4, int total4) {
  int i = blockIdx.x * 256 + threadIdx.x;
  if (i >= total4) return;
  float4 v = xloc4[i];
  float4 g = ga4[i & 63];
  v.x *= g.x; v.y *= g.y; v.z *= g.z; v.w *= g.w;
  out4[i] = v;
}

extern "C" void kernel_launch(void* const* d_in, const int* in_sizes, int n_in,
                              void* d_out, int out_size, void* d_ws, size_t ws_size,
                              hipStream_t stream) {
  const float* x      = (const float*)d_in[0];
  const int* edge_idx = (const int*)d_in[1];
  const float* W      = (const float*)d_in[4];
  const float* a_src  = (const float*)d_in[5];
  const float* a_dst  = (const float*)d_in[6];
  const float* conv_b = (const float*)d_in[7];
  const float* fc_w   = (const float*)d_in[8];
  const float* fc_b   = (const float*)d_in[9];
  const float* ln_w   = (const float*)d_in[10];
  const float* ln_b   = (const float*)d_in[11];
  const float* gate_w = (const float*)d_in[12];
  const float* gate_b = (const float*)d_in[13];
  const float* gfc_w  = (const float*)d_in[14];
  const float* gfc_b  = (const float*)d_in[15];
  (void)n_in; (void)out_size; (void)ws_size;

  int N = in_sizes[0] / 128;
  int E = in_sizes[1] / 2;
  const int* src = edge_idx;
  const int* dst = edge_idx + E;

  char* p = (char*)d_ws;
  auto alloc = [&](size_t bytes) -> char* {
    char* r = p;
    p += (bytes + 255) & ~(size_t)255;
    return r;
  };
  float*          z1   = (float*)alloc((size_t)N * 256 * 4);          // gemm1 out
  float*          xloc = (float*)alloc((size_t)N * 256 * 4);          // conv out / x3 / final x
  unsigned short* xpb  = (unsigned short*)alloc((size_t)N * 256 * 2); // bf16 xp
  unsigned short* x2b  = (unsigned short*)alloc((size_t)N * 256 * 2); // bf16 x2
  float* asrc  = (float*)alloc((size_t)N * 8 * 4);
  float* adst  = (float*)alloc((size_t)N * 8 * 4);
  unsigned short* Wb   = (unsigned short*)alloc(256 * 128 * 2);
  unsigned short* fcB  = (unsigned short*)alloc(256 * 256 * 2);
  float* gfcT  = (float*)alloc(256 * 256 * 4);
  float* egate = (float*)alloc((size_t)N * 4);
  int*   deg   = (int*)alloc((size_t)N * 4);
  int*   offs  = (int*)alloc((size_t)(N + 1) * 4);
  int*   curs  = (int*)alloc((size_t)N * 4);
  int*   ssrc  = (int*)alloc((size_t)E * 4);
  float* Ssum  = (float*)alloc(256);
  float* xg    = (float*)alloc(1024);
  float* ga    = (float*)alloc(1024);

  int nb = (N + 255) / 256;
  int eb = (E + 255) / 256;
  dim3 mgrid((N + 127) / 128, 2);

  repack_kernel<<<(256 * 128 + 2 * 256 * 256 + 255) / 256, 256, 0, stream>>>(
      W, fc_w, gfc_w, Wb, fcB, gfcT);
  zero_kernel<<<nb, 256, 0, stream>>>(deg, xg, Ssum, N);
  // xp(bf16) = x @ W
  mfma_gemm<0, 1, 0><<<mgrid, 256, 0, stream>>>(x, Wb, nullptr, xpb, N, 128, 0.f);
  alpha_kernel<<<(N * 8 + 255) / 256, 256, 0, stream>>>(
      xpb, (const float4*)a_src, (const float4*)a_dst, asrc, adst, N);
  hist_kernel<<<eb, 256, 0, stream>>>(dst, deg, E);
  scan_kernel<<<1, 1024, 0, stream>>>(deg, offs, curs, N);
  scatter_kernel<<<eb, 256, 0, stream>>>(src, dst, curs, ssrc, E);
  agg_kernel<<<(N + 3) / 4, 256, 0, stream>>>(
      xpb, asrc, adst, offs, ssrc, (const float4*)conv_b, (float4*)xloc, N);
  // z1 = leaky(xloc@fc^T + b, 0.01)
  mfma_gemm<0, 0, 1><<<mgrid, 256, 0, stream>>>(xloc, fcB, fc_b, z1, N, 256, 0.01f);
  rowsm_kernel<<<(N + 3) / 4, 256, 0, stream>>>(
      (const float4*)z1, (const float4*)xloc, x2b, N);
  // x3 = x2@fc^T + b  (overwrites xloc)
  mfma_gemm<1, 0, 0><<<mgrid, 256, 0, stream>>>(x2b, fcB, fc_b, xloc, N, 256, 0.f);
  ln_kernel<<<(N + 3) / 4, 256, 0, stream>>>(
      (float4*)xloc, (const float4*)ln_w, (const float4*)ln_b,
      (const float4*)gate_w, gate_b, egate, N);
  pool_kernel<<<128, 256, 0, stream>>>(xloc, egate, xg, Ssum, N);
  gfc_kernel<<<1, 256, 0, stream>>>(xg, Ssum, gfcT, gfc_b, ga);
  out_kernel<<<(N * 64 + 255) / 256, 256, 0, stream>>>(
      (const float4*)xloc, (const float4*)ga, (float4*)d_out, N * 64);
}

// Round 5
// 360.033 us; speedup vs baseline: 2.5704x; 1.0825x over previous
//
#include <hip/hip_runtime.h>

// ---------------------------------------------------------------------------
// GAT pipeline. N=30000, E=600000, IN=128, H=8, HD=32, OUT=256.
// R1: removed per-node scalar atomic (925->549us).
// R2: bf16 MFMA GEMMs + bf16 gather (549->414us).
// R3: agg edge-loop software-pipelined x4; copy_kernel folded into scan.
// R4: pool_kernel 128->512 blocks (was 5% occupancy, 58us latency-bound);
//     agg unroll x8 (8 gathers in flight).
// ---------------------------------------------------------------------------

typedef __attribute__((ext_vector_type(8))) short bf16x8;   // 8 bf16 (4 VGPRs)
typedef __attribute__((ext_vector_type(4))) float f32x4;    // MFMA acc

__device__ __forceinline__ float leaky_f(float v, float s) { return v > 0.f ? v : s * v; }
__device__ __forceinline__ unsigned short f2bf(float f) {   // RNE, no NaN expected
  unsigned int u = __float_as_uint(f);
  u += 0x7fffu + ((u >> 16) & 1u);
  return (unsigned short)(u >> 16);
}
__device__ __forceinline__ float bf2f(unsigned short u) {
  return __uint_as_float(((unsigned int)u) << 16);
}

// ---- repack: Wb[c][k]=bf16(W[h][k][d]) (c=h*32+d); fcB=bf16(fc_w) same layout
// ([o][i] == B[n][k]); gfcT fp32 transpose for the tiny gfc kernel.
__global__ void repack_kernel(const float* __restrict__ W, const float* __restrict__ fc_w,
                              const float* __restrict__ gfc_w, unsigned short* __restrict__ Wb,
                              unsigned short* __restrict__ fcB, float* __restrict__ gfcT) {
  int i = blockIdx.x * 256 + threadIdx.x;
  if (i < 256 * 128) {
    int c = i >> 7, k = i & 127;
    Wb[i] = f2bf(W[((c >> 5) * 128 + k) * 32 + (c & 31)]);
  } else if (i < 256 * 128 + 256 * 256) {
    int j = i - 256 * 128;
    fcB[j] = f2bf(fc_w[j]);
  } else if (i < 256 * 128 + 2 * 256 * 256) {
    int j = i - 256 * 128 - 256 * 256;
    gfcT[j] = gfc_w[(j & 255) * 256 + (j >> 8)];
  }
}

__global__ void zero_kernel(int* __restrict__ deg, float* __restrict__ xg,
                            float* __restrict__ S, int n) {
  int i = blockIdx.x * 256 + threadIdx.x;
  if (i < n) deg[i] = 0;
  if (i < 256) xg[i] = 0.f;
  if (i == 0) S[0] = 0.f;
}

// ---- bf16 MFMA GEMM: C[n_rows,256] = act(A[n_rows,K] @ B^T + bias)
// B given as bf16 [256][K] (n-major, k contiguous). 128x128 tile / block,
// 4 waves, each wave 64x64 = 4x4 MFMA tiles of 16x16x32. fp32 accumulate.
template <int A_BF16, int OUT_BF16, int ACT>
__global__ __launch_bounds__(256) void mfma_gemm(
    const void* __restrict__ Av, const unsigned short* __restrict__ B,
    const float* __restrict__ bias, void* __restrict__ Cv,
    int n_rows, int K, float slope) {
  __shared__ short As[128][72];  // +8 bf16 pad: 144B row stride, ~2-way banks
  __shared__ short Bs[128][72];
  int t = threadIdx.x;
  int wave = t >> 6, lane = t & 63;
  int m16 = lane & 15, quad = lane >> 4;
  int row0 = blockIdx.x * 128, col0 = blockIdx.y * 128;
  int wr = (wave >> 1) * 64, wc = (wave & 1) * 64;

  f32x4 acc[4][4];
#pragma unroll
  for (int i = 0; i < 4; ++i)
#pragma unroll
    for (int j = 0; j < 4; ++j) acc[i][j] = (f32x4){0.f, 0.f, 0.f, 0.f};

  for (int k0 = 0; k0 < K; k0 += 64) {
    if (A_BF16) {
      const unsigned short* A = (const unsigned short*)Av;
#pragma unroll
      for (int p = 0; p < 4; ++p) {
        int e = (p * 256 + t) * 8;
        int row = e >> 6, k = e & 63;
        int ar = row0 + row; if (ar > n_rows - 1) ar = n_rows - 1;
        uint4 q = *(const uint4*)(A + (size_t)ar * K + k0 + k);
        *(uint4*)&As[row][k] = q;
      }
    } else {
      const float* A = (const float*)Av;
#pragma unroll
      for (int p = 0; p < 8; ++p) {
        int e = (p * 256 + t) * 4;
        int row = e >> 6, k = e & 63;
        int ar = row0 + row; if (ar > n_rows - 1) ar = n_rows - 1;
        float4 q = *(const float4*)(A + (size_t)ar * K + k0 + k);
        unsigned int lo = (unsigned int)f2bf(q.x) | ((unsigned int)f2bf(q.y) << 16);
        unsigned int hi = (unsigned int)f2bf(q.z) | ((unsigned int)f2bf(q.w) << 16);
        *(uint2*)&As[row][k] = make_uint2(lo, hi);
      }
    }
#pragma unroll
    for (int p = 0; p < 4; ++p) {
      int e = (p * 256 + t) * 8;
      int nn = e >> 6, k = e & 63;
      uint4 q = *(const uint4*)(B + (size_t)(col0 + nn) * K + k0 + k);
      *(uint4*)&Bs[nn][k] = q;
    }
    __syncthreads();
#pragma unroll
    for (int ks = 0; ks < 64; ks += 32) {
      bf16x8 af[4], bf[4];
#pragma unroll
      for (int i = 0; i < 4; ++i)
        af[i] = *(const bf16x8*)&As[wr + i * 16 + m16][ks + quad * 8];
#pragma unroll
      for (int j = 0; j < 4; ++j)
        bf[j] = *(const bf16x8*)&Bs[wc + j * 16 + m16][ks + quad * 8];
#pragma unroll
      for (int i = 0; i < 4; ++i)
#pragma unroll
        for (int j = 0; j < 4; ++j)
          acc[i][j] = __builtin_amdgcn_mfma_f32_16x16x32_bf16(af[i], bf[j], acc[i][j], 0, 0, 0);
    }
    __syncthreads();
  }
  // ---- epilogue: C/D layout col=lane&15, row=quad*4+reg
#pragma unroll
  for (int j = 0; j < 4; ++j) {
    int c = col0 + wc + j * 16 + m16;
    float bv = bias ? bias[c] : 0.f;
#pragma unroll
    for (int i = 0; i < 4; ++i) {
#pragma unroll
      for (int v = 0; v < 4; ++v) {
        int r = row0 + wr + i * 16 + quad * 4 + v;
        if (r < n_rows) {
          float val = acc[i][j][v] + bv;
          if (ACT) val = leaky_f(val, slope);
          if (OUT_BF16)
            ((unsigned short*)Cv)[(size_t)r * 256 + c] = f2bf(val);
          else
            ((float*)Cv)[(size_t)r * 256 + c] = val;
        }
      }
    }
  }
}

// ---- alpha from bf16 xp
__global__ void alpha_kernel(const unsigned short* __restrict__ xpb,
                             const float4* __restrict__ as4, const float4* __restrict__ ad4,
                             float* __restrict__ alpha_src, float* __restrict__ alpha_dst,
                             int n_nodes) {
  int i = blockIdx.x * 256 + threadIdx.x;
  if (i >= n_nodes * 8) return;
  int n = i >> 3, h = i & 7;
  const ushort4* xr = (const ushort4*)(xpb + (size_t)n * 256 + h * 32);
  float s = 0.f, d = 0.f;
#pragma unroll
  for (int j = 0; j < 8; ++j) {
    ushort4 q = xr[j];
    float4 a = as4[h * 8 + j];
    float4 b = ad4[h * 8 + j];
    float vx = bf2f(q.x), vy = bf2f(q.y), vz = bf2f(q.z), vw = bf2f(q.w);
    s += vx * a.x + vy * a.y + vz * a.z + vw * a.w;
    d += vx * b.x + vy * b.y + vz * b.z + vw * b.w;
  }
  alpha_src[i] = s;
  alpha_dst[i] = d;
}

// ---- CSR build
__global__ void hist_kernel(const int* __restrict__ dst, int* __restrict__ deg, int e) {
  int i = blockIdx.x * 256 + threadIdx.x;
  if (i < e) atomicAdd(&deg[dst[i]], 1);
}

// scan also emits curs[i] = offsets[i] (exclusive prefix), saving a copy pass
__global__ __launch_bounds__(1024) void scan_kernel(const int* __restrict__ deg,
                                                    int* __restrict__ offsets,
                                                    int* __restrict__ curs, int n) {
  __shared__ int wsum[16];
  __shared__ int carry_s;
  int t = threadIdx.x, lane = t & 63, wv = t >> 6;
  if (t == 0) { carry_s = 0; offsets[0] = 0; }
  __syncthreads();
  for (int base = 0; base < n; base += 4096) {
    int i0 = base + t * 4;
    int4 v = make_int4(0, 0, 0, 0);
    if (i0 + 3 < n) v = *(const int4*)(deg + i0);
    else {
      if (i0 < n) v.x = deg[i0];
      if (i0 + 1 < n) v.y = deg[i0 + 1];
      if (i0 + 2 < n) v.z = deg[i0 + 2];
    }
    int p1 = v.x, p2 = p1 + v.y, p3 = p2 + v.z, p4 = p3 + v.w;
    int s = p4;
#pragma unroll
    for (int d = 1; d < 64; d <<= 1) {
      int u = __shfl_up(s, d);
      if (lane >= d) s += u;
    }
    if (lane == 63) wsum[wv] = s;
    __syncthreads();
    int woff = 0, total = 0;
#pragma unroll
    for (int k = 0; k < 16; ++k) {
      int wsk = wsum[k];
      woff += (k < wv) ? wsk : 0;
      total += wsk;
    }
    int carry = carry_s;
    int excl = carry + woff + s - p4;  // exclusive prefix before this thread's 4
    if (i0 < n)     { offsets[i0 + 1] = excl + p1; curs[i0]     = excl; }
    if (i0 + 1 < n) { offsets[i0 + 2] = excl + p2; curs[i0 + 1] = excl + p1; }
    if (i0 + 2 < n) { offsets[i0 + 3] = excl + p3; curs[i0 + 2] = excl + p2; }
    if (i0 + 3 < n) { offsets[i0 + 4] = excl + p4; curs[i0 + 3] = excl + p3; }
    __syncthreads();
    if (t == 0) carry_s = carry + total;
    __syncthreads();
  }
}

__global__ void scatter_kernel(const int* __restrict__ src, const int* __restrict__ dst,
                               int* __restrict__ cursor, int* __restrict__ ssrc, int e) {
  int i = blockIdx.x * 256 + threadIdx.x;
  if (i < e) {
    int p = atomicAdd(&cursor[dst[i]], 1);
    ssrc[p] = src[i];
  }
}

// ---- edge aggregation, bf16 gather, fp32 accumulate. Edge loop unrolled x8
// then x4 then scalar: up to 8 independent 512B gathers in flight per wave.
__global__ __launch_bounds__(256) void agg_kernel(
    const unsigned short* __restrict__ xpb, const float* __restrict__ asrc,
    const float* __restrict__ adst, const int* __restrict__ offsets,
    const int* __restrict__ ssrc, const float4* __restrict__ conv_b4,
    float4* __restrict__ xloc4, int n_nodes) {
  int lane = threadIdx.x & 63, w = threadIdx.x >> 6;
  int n = blockIdx.x * 4 + w;
  if (n >= n_nodes) return;
  int h = lane >> 3;
  float ad = adst[n * 8 + h];
  float p = __expf(leaky_f(asrc[n * 8 + h] + ad, 0.2f));
  ushort4 xq = ((const ushort4*)(xpb + (size_t)n * 256))[lane];
  float4 acc;
  acc.x = p * bf2f(xq.x); acc.y = p * bf2f(xq.y);
  acc.z = p * bf2f(xq.z); acc.w = p * bf2f(xq.w);
  float ssum = p;
  int beg = offsets[n], end = offsets[n + 1];
  int j = beg;
  for (; j + 8 <= end; j += 8) {
    int sv[8];
#pragma unroll
    for (int u = 0; u < 8; ++u) sv[u] = ssrc[j + u];
    float a[8];
#pragma unroll
    for (int u = 0; u < 8; ++u) a[u] = asrc[sv[u] * 8 + h];
    ushort4 q[8];
#pragma unroll
    for (int u = 0; u < 8; ++u) q[u] = ((const ushort4*)(xpb + (size_t)sv[u] * 256))[lane];
#pragma unroll
    for (int u = 0; u < 8; ++u) {
      float pu = __expf(leaky_f(a[u] + ad, 0.2f));
      acc.x += pu * bf2f(q[u].x); acc.y += pu * bf2f(q[u].y);
      acc.z += pu * bf2f(q[u].z); acc.w += pu * bf2f(q[u].w);
      ssum += pu;
    }
  }
  for (; j + 4 <= end; j += 4) {
    int sv0 = ssrc[j], sv1 = ssrc[j + 1], sv2 = ssrc[j + 2], sv3 = ssrc[j + 3];
    float a0 = asrc[sv0 * 8 + h];
    float a1 = asrc[sv1 * 8 + h];
    float a2 = asrc[sv2 * 8 + h];
    float a3 = asrc[sv3 * 8 + h];
    ushort4 q0 = ((const ushort4*)(xpb + (size_t)sv0 * 256))[lane];
    ushort4 q1 = ((const ushort4*)(xpb + (size_t)sv1 * 256))[lane];
    ushort4 q2 = ((const ushort4*)(xpb + (size_t)sv2 * 256))[lane];
    ushort4 q3 = ((const ushort4*)(xpb + (size_t)sv3 * 256))[lane];
    float p0 = __expf(leaky_f(a0 + ad, 0.2f));
    float p1 = __expf(leaky_f(a1 + ad, 0.2f));
    float p2 = __expf(leaky_f(a2 + ad, 0.2f));
    float p3 = __expf(leaky_f(a3 + ad, 0.2f));
    acc.x += p0 * bf2f(q0.x); acc.y += p0 * bf2f(q0.y);
    acc.z += p0 * bf2f(q0.z); acc.w += p0 * bf2f(q0.w);
    acc.x += p1 * bf2f(q1.x); acc.y += p1 * bf2f(q1.y);
    acc.z += p1 * bf2f(q1.z); acc.w += p1 * bf2f(q1.w);
    acc.x += p2 * bf2f(q2.x); acc.y += p2 * bf2f(q2.y);
    acc.z += p2 * bf2f(q2.z); acc.w += p2 * bf2f(q2.w);
    acc.x += p3 * bf2f(q3.x); acc.y += p3 * bf2f(q3.y);
    acc.z += p3 * bf2f(q3.z); acc.w += p3 * bf2f(q3.w);
    ssum += p0 + p1 + p2 + p3;
  }
  for (; j < end; ++j) {
    int sv = ssrc[j];
    float a1 = asrc[sv * 8 + h];
    ushort4 q = ((const ushort4*)(xpb + (size_t)sv * 256))[lane];
    float p1 = __expf(leaky_f(a1 + ad, 0.2f));
    acc.x += p1 * bf2f(q.x); acc.y += p1 * bf2f(q.y);
    acc.z += p1 * bf2f(q.z); acc.w += p1 * bf2f(q.w);
    ssum += p1;
  }
  float inv = 1.f / (ssum + 1e-16f);
  float4 b = conv_b4[lane];
  float4 o;
  o.x = acc.x * inv + b.x; o.y = acc.y * inv + b.y;
  o.z = acc.z * inv + b.z; o.w = acc.w * inv + b.w;
  xloc4[(size_t)n * 64 + lane] = o;
}

// ---- row softmax of z1 (already leaky 0.01), x2 = leaky(xloc*sa, 0.2) -> bf16
__global__ __launch_bounds__(256) void rowsm_kernel(const float4* __restrict__ z1,
                                                    const float4* __restrict__ xloc,
                                                    unsigned short* __restrict__ x2b,
                                                    int n_nodes) {
  int lane = threadIdx.x & 63, w = threadIdx.x >> 6;
  int n = blockIdx.x * 4 + w;
  if (n >= n_nodes) return;
  size_t idx = (size_t)n * 64 + lane;
  float4 z = z1[idx];
  float m = fmaxf(fmaxf(z.x, z.y), fmaxf(z.z, z.w));
#pragma unroll
  for (int mk = 1; mk < 64; mk <<= 1) m = fmaxf(m, __shfl_xor(m, mk));
  float4 e;
  e.x = __expf(z.x - m); e.y = __expf(z.y - m);
  e.z = __expf(z.z - m); e.w = __expf(z.w - m);
  float s = e.x + e.y + e.z + e.w;
#pragma unroll
  for (int mk = 1; mk < 64; mk <<= 1) s += __shfl_xor(s, mk);
  float inv = 1.f / s;
  float4 xv = xloc[idx];
  ushort4 r;
  r.x = f2bf(leaky_f(xv.x * e.x * inv, 0.2f));
  r.y = f2bf(leaky_f(xv.y * e.y * inv, 0.2f));
  r.z = f2bf(leaky_f(xv.z * e.z * inv, 0.2f));
  r.w = f2bf(leaky_f(xv.w * e.w * inv, 0.2f));
  ((ushort4*)x2b)[idx] = r;
}

// ---- LayerNorm + L2 normalize + gate logit, in-place fp32.
__global__ __launch_bounds__(256) void ln_kernel(
    float4* __restrict__ xloc4, const float4* __restrict__ lnw4,
    const float4* __restrict__ lnb4, const float4* __restrict__ gatew4,
    const float* __restrict__ gate_b, float* __restrict__ egate, int n_nodes) {
  int lane = threadIdx.x & 63, w = threadIdx.x >> 6;
  int n = blockIdx.x * 4 + w;
  if (n >= n_nodes) return;
  size_t idx = (size_t)n * 64 + lane;
  float4 v = xloc4[idx];
  float s = v.x + v.y + v.z + v.w;
#pragma unroll
  for (int mk = 1; mk < 64; mk <<= 1) s += __shfl_xor(s, mk);
  float mu = s * (1.f / 256.f);
  float4 c;
  c.x = v.x - mu; c.y = v.y - mu; c.z = v.z - mu; c.w = v.w - mu;
  float q = c.x * c.x + c.y * c.y + c.z * c.z + c.w * c.w;
#pragma unroll
  for (int mk = 1; mk < 64; mk <<= 1) q += __shfl_xor(q, mk);
  float rstd = rsqrtf(q * (1.f / 256.f) + 1e-5f);
  float4 lw = lnw4[lane], lb = lnb4[lane];
  float4 y;
  y.x = c.x * rstd * lw.x + lb.x; y.y = c.y * rstd * lw.y + lb.y;
  y.z = c.z * rstd * lw.z + lb.z; y.w = c.w * rstd * lw.w + lb.w;
  float n2 = y.x * y.x + y.y * y.y + y.z * y.z + y.w * y.w;
#pragma unroll
  for (int mk = 1; mk < 64; mk <<= 1) n2 += __shfl_xor(n2, mk);
  float inv = 1.f / fmaxf(sqrtf(n2), 1e-12f);
  y.x *= inv; y.y *= inv; y.z *= inv; y.w *= inv;
  xloc4[idx] = y;
  float4 gw = gatew4[lane];
  float gp = y.x * gw.x + y.y * gw.y + y.z * gw.z + y.w * gw.w;
#pragma unroll
  for (int mk = 1; mk < 64; mk <<= 1) gp += __shfl_xor(gp, mk);
  if (lane == 0) egate[n] = __expf(gp + gate_b[0]);  // |gp| <= ~0.8, safe
}

// ---- pooling + Ssum: per-block partials, one atomic per thread per block.
// 512 blocks (was 128: 5% occupancy, latency-bound at 58us).
__global__ __launch_bounds__(256) void pool_kernel(const float* __restrict__ xloc,
                                                   const float* __restrict__ egate,
                                                   float* __restrict__ xg,
                                                   float* __restrict__ Ssum, int n) {
  int c = threadIdx.x;
  int rpb = (n + (int)gridDim.x - 1) / (int)gridDim.x;
  int r0 = blockIdx.x * rpb;
  int r1 = r0 + rpb; if (r1 > n) r1 = n;
  float acc = 0.f, gs = 0.f;
  for (int r = r0; r < r1; ++r) {
    float g = egate[r];
    acc += g * xloc[(size_t)r * 256 + c];
    gs += g;
  }
  atomicAdd(&xg[c], acc);
  if (c == 0) atomicAdd(Ssum, gs);
}

__global__ __launch_bounds__(256) void gfc_kernel(const float* __restrict__ xg,
                                                  const float* __restrict__ S,
                                                  const float* __restrict__ gfcT,
                                                  const float* __restrict__ gfc_b,
                                                  float* __restrict__ ga) {
  __shared__ float xs[256];
  __shared__ float red[256];
  int t = threadIdx.x;
  float invS = 1.f / (S[0] + 1e-16f);
  xs[t] = xg[t] * invS;
  __syncthreads();
  float acc = gfc_b[t];
  for (int i = 0; i < 256; ++i) acc += xs[i] * gfcT[i * 256 + t];
  acc = fmaxf(acc, 0.f);
  red[t] = acc;
  __syncthreads();
  for (int s = 128; s > 0; s >>= 1) {
    if (t < s) red[t] = fmaxf(red[t], red[t + s]);
    __syncthreads();
  }
  float m = red[0];
  __syncthreads();
  float e = __expf(acc - m);
  red[t] = e;
  __syncthreads();
  for (int s = 128; s > 0; s >>= 1) {
    if (t < s) red[t] += red[t + s];
    __syncthreads();
  }
  ga[t] = e / red[0];
}

__global__ void out_kernel(const float4* __restrict__ xloc4, const float4* __restrict__ ga4,
                           float4* __restrict__ out4, int total4) {
  int i = blockIdx.x * 256 + threadIdx.x;
  if (i >= total4) return;
  float4 v = xloc4[i];
  float4 g = ga4[i & 63];
  v.x *= g.x; v.y *= g.y; v.z *= g.z; v.w *= g.w;
  out4[i] = v;
}

extern "C" void kernel_launch(void* const* d_in, const int* in_sizes, int n_in,
                              void* d_out, int out_size, void* d_ws, size_t ws_size,
                              hipStream_t stream) {
  const float* x      = (const float*)d_in[0];
  const int* edge_idx = (const int*)d_in[1];
  const float* W      = (const float*)d_in[4];
  const float* a_src  = (const float*)d_in[5];
  const float* a_dst  = (const float*)d_in[6];
  const float* conv_b = (const float*)d_in[7];
  const float* fc_w   = (const float*)d_in[8];
  const float* fc_b   = (const float*)d_in[9];
  const float* ln_w   = (const float*)d_in[10];
  const float* ln_b   = (const float*)d_in[11];
  const float* gate_w = (const float*)d_in[12];
  const float* gate_b = (const float*)d_in[13];
  const float* gfc_w  = (const float*)d_in[14];
  const float* gfc_b  = (const float*)d_in[15];
  (void)n_in; (void)out_size; (void)ws_size;

  int N = in_sizes[0] / 128;
  int E = in_sizes[1] / 2;
  const int* src = edge_idx;
  const int* dst = edge_idx + E;

  char* p = (char*)d_ws;
  auto alloc = [&](size_t bytes) -> char* {
    char* r = p;
    p += (bytes + 255) & ~(size_t)255;
    return r;
  };
  float*          z1   = (float*)alloc((size_t)N * 256 * 4);          // gemm1 out
  float*          xloc = (float*)alloc((size_t)N * 256 * 4);          // conv out / x3 / final x
  unsigned short* xpb  = (unsigned short*)alloc((size_t)N * 256 * 2); // bf16 xp
  unsigned short* x2b  = (unsigned short*)alloc((size_t)N * 256 * 2); // bf16 x2
  float* asrc  = (float*)alloc((size_t)N * 8 * 4);
  float* adst  = (float*)alloc((size_t)N * 8 * 4);
  unsigned short* Wb   = (unsigned short*)alloc(256 * 128 * 2);
  unsigned short* fcB  = (unsigned short*)alloc(256 * 256 * 2);
  float* gfcT  = (float*)alloc(256 * 256 * 4);
  float* egate = (float*)alloc((size_t)N * 4);
  int*   deg   = (int*)alloc((size_t)N * 4);
  int*   offs  = (int*)alloc((size_t)(N + 1) * 4);
  int*   curs  = (int*)alloc((size_t)N * 4);
  int*   ssrc  = (int*)alloc((size_t)E * 4);
  float* Ssum  = (float*)alloc(256);
  float* xg    = (float*)alloc(1024);
  float* ga    = (float*)alloc(1024);

  int nb = (N + 255) / 256;
  int eb = (E + 255) / 256;
  dim3 mgrid((N + 127) / 128, 2);

  repack_kernel<<<(256 * 128 + 2 * 256 * 256 + 255) / 256, 256, 0, stream>>>(
      W, fc_w, gfc_w, Wb, fcB, gfcT);
  zero_kernel<<<nb, 256, 0, stream>>>(deg, xg, Ssum, N);
  // xp(bf16) = x @ W
  mfma_gemm<0, 1, 0><<<mgrid, 256, 0, stream>>>(x, Wb, nullptr, xpb, N, 128, 0.f);
  alpha_kernel<<<(N * 8 + 255) / 256, 256, 0, stream>>>(
      xpb, (const float4*)a_src, (const float4*)a_dst, asrc, adst, N);
  hist_kernel<<<eb, 256, 0, stream>>>(dst, deg, E);
  scan_kernel<<<1, 1024, 0, stream>>>(deg, offs, curs, N);
  scatter_kernel<<<eb, 256, 0, stream>>>(src, dst, curs, ssrc, E);
  agg_kernel<<<(N + 3) / 4, 256, 0, stream>>>(
      xpb, asrc, adst, offs, ssrc, (const float4*)conv_b, (float4*)xloc, N);
  // z1 = leaky(xloc@fc^T + b, 0.01)
  mfma_gemm<0, 0, 1><<<mgrid, 256, 0, stream>>>(xloc, fcB, fc_b, z1, N, 256, 0.01f);
  rowsm_kernel<<<(N + 3) / 4, 256, 0, stream>>>(
      (const float4*)z1, (const float4*)xloc, x2b, N);
  // x3 = x2@fc^T + b  (overwrites xloc)
  mfma_gemm<1, 0, 0><<<mgrid, 256, 0, stream>>>(x2b, fcB, fc_b, xloc, N, 256, 0.f);
  ln_kernel<<<(N + 3) / 4, 256, 0, stream>>>(
      (float4*)xloc, (const float4*)ln_w, (const float4*)ln_b,
      (const float4*)gate_w, gate_b, egate, N);
  pool_kernel<<<512, 256, 0, stream>>>(xloc, egate, xg, Ssum, N);
  gfc_kernel<<<1, 256, 0, stream>>>(xg, Ssum, gfcT, gfc_b, ga);
  out_kernel<<<(N * 64 + 255) / 256, 256, 0, stream>>>(
      (const float4*)xloc, (const float4*)ga, (float4*)d_out, N * 64);
}

// Round 6
// 334.580 us; speedup vs baseline: 2.7659x; 1.0761x over previous
//
#include <hip/hip_runtime.h>

// ---------------------------------------------------------------------------
// GAT pipeline. N=30000, E=600000, IN=128, H=8, HD=32, OUT=256.
// R1: removed per-node scalar atomic (925->549us).
// R2: bf16 MFMA GEMMs + bf16 gather (549->414us).
// R3: agg edge-loop software-pipelined x4; copy folded into scan.
// R4: pool 512 blocks; agg unroll x8 (390->360us).
// R5: (a) per-edge softmax weights precomputed in scatter (pexp) -> agg's
//     hot loop is pure gather+fma; (b) GEMM1+rowsoftmax and GEMM2+LN fused
//     via 64x256 tiles (z1 buffer + 2 dispatches eliminated).
// ---------------------------------------------------------------------------

typedef __attribute__((ext_vector_type(8))) short bf16x8;   // 8 bf16 (4 VGPRs)
typedef __attribute__((ext_vector_type(4))) float f32x4;    // MFMA acc

__device__ __forceinline__ float leaky_f(float v, float s) { return v > 0.f ? v : s * v; }
__device__ __forceinline__ unsigned short f2bf(float f) {   // RNE, no NaN expected
  unsigned int u = __float_as_uint(f);
  u += 0x7fffu + ((u >> 16) & 1u);
  return (unsigned short)(u >> 16);
}
__device__ __forceinline__ float bf2f(unsigned short u) {
  return __uint_as_float(((unsigned int)u) << 16);
}
__device__ __forceinline__ float red16_sum(float v) {
#pragma unroll
  for (int m = 1; m < 16; m <<= 1) v += __shfl_xor(v, m);
  return v;
}
__device__ __forceinline__ float red16_max(float v) {
#pragma unroll
  for (int m = 1; m < 16; m <<= 1) v = fmaxf(v, __shfl_xor(v, m));
  return v;
}

// ---- repack: Wb[c][k]=bf16(W[h][k][d]) (c=h*32+d); fcB=bf16(fc_w) ([o][i]);
// gfcT fp32 transpose for the tiny gfc kernel.
__global__ void repack_kernel(const float* __restrict__ W, const float* __restrict__ fc_w,
                              const float* __restrict__ gfc_w, unsigned short* __restrict__ Wb,
                              unsigned short* __restrict__ fcB, float* __restrict__ gfcT) {
  int i = blockIdx.x * 256 + threadIdx.x;
  if (i < 256 * 128) {
    int c = i >> 7, k = i & 127;
    Wb[i] = f2bf(W[((c >> 5) * 128 + k) * 32 + (c & 31)]);
  } else if (i < 256 * 128 + 256 * 256) {
    int j = i - 256 * 128;
    fcB[j] = f2bf(fc_w[j]);
  } else if (i < 256 * 128 + 2 * 256 * 256) {
    int j = i - 256 * 128 - 256 * 256;
    gfcT[j] = gfc_w[(j & 255) * 256 + (j >> 8)];
  }
}

__global__ void zero_kernel(int* __restrict__ deg, float* __restrict__ xg,
                            float* __restrict__ S, int n) {
  int i = blockIdx.x * 256 + threadIdx.x;
  if (i < n) deg[i] = 0;
  if (i < 256) xg[i] = 0.f;
  if (i == 0) S[0] = 0.f;
}

// ---- GEMM0 (xp = x @ W): 128x128 tile, unchanged from R4.
template <int A_BF16, int OUT_BF16, int ACT>
__global__ __launch_bounds__(256) void mfma_gemm(
    const void* __restrict__ Av, const unsigned short* __restrict__ B,
    const float* __restrict__ bias, void* __restrict__ Cv,
    int n_rows, int K, float slope) {
  __shared__ short As[128][72];
  __shared__ short Bs[128][72];
  int t = threadIdx.x;
  int wave = t >> 6, lane = t & 63;
  int m16 = lane & 15, quad = lane >> 4;
  int row0 = blockIdx.x * 128, col0 = blockIdx.y * 128;
  int wr = (wave >> 1) * 64, wc = (wave & 1) * 64;

  f32x4 acc[4][4];
#pragma unroll
  for (int i = 0; i < 4; ++i)
#pragma unroll
    for (int j = 0; j < 4; ++j) acc[i][j] = (f32x4){0.f, 0.f, 0.f, 0.f};

  for (int k0 = 0; k0 < K; k0 += 64) {
    if (A_BF16) {
      const unsigned short* A = (const unsigned short*)Av;
#pragma unroll
      for (int p = 0; p < 4; ++p) {
        int e = (p * 256 + t) * 8;
        int row = e >> 6, k = e & 63;
        int ar = row0 + row; if (ar > n_rows - 1) ar = n_rows - 1;
        uint4 q = *(const uint4*)(A + (size_t)ar * K + k0 + k);
        *(uint4*)&As[row][k] = q;
      }
    } else {
      const float* A = (const float*)Av;
#pragma unroll
      for (int p = 0; p < 8; ++p) {
        int e = (p * 256 + t) * 4;
        int row = e >> 6, k = e & 63;
        int ar = row0 + row; if (ar > n_rows - 1) ar = n_rows - 1;
        float4 q = *(const float4*)(A + (size_t)ar * K + k0 + k);
        unsigned int lo = (unsigned int)f2bf(q.x) | ((unsigned int)f2bf(q.y) << 16);
        unsigned int hi = (unsigned int)f2bf(q.z) | ((unsigned int)f2bf(q.w) << 16);
        *(uint2*)&As[row][k] = make_uint2(lo, hi);
      }
    }
#pragma unroll
    for (int p = 0; p < 4; ++p) {
      int e = (p * 256 + t) * 8;
      int nn = e >> 6, k = e & 63;
      uint4 q = *(const uint4*)(B + (size_t)(col0 + nn) * K + k0 + k);
      *(uint4*)&Bs[nn][k] = q;
    }
    __syncthreads();
#pragma unroll
    for (int ks = 0; ks < 64; ks += 32) {
      bf16x8 af[4], bf[4];
#pragma unroll
      for (int i = 0; i < 4; ++i)
        af[i] = *(const bf16x8*)&As[wr + i * 16 + m16][ks + quad * 8];
#pragma unroll
      for (int j = 0; j < 4; ++j)
        bf[j] = *(const bf16x8*)&Bs[wc + j * 16 + m16][ks + quad * 8];
#pragma unroll
      for (int i = 0; i < 4; ++i)
#pragma unroll
        for (int j = 0; j < 4; ++j)
          acc[i][j] = __builtin_amdgcn_mfma_f32_16x16x32_bf16(af[i], bf[j], acc[i][j], 0, 0, 0);
    }
    __syncthreads();
  }
#pragma unroll
  for (int j = 0; j < 4; ++j) {
    int c = col0 + wc + j * 16 + m16;
    float bv = bias ? bias[c] : 0.f;
#pragma unroll
    for (int i = 0; i < 4; ++i) {
#pragma unroll
      for (int v = 0; v < 4; ++v) {
        int r = row0 + wr + i * 16 + quad * 4 + v;
        if (r < n_rows) {
          float val = acc[i][j][v] + bv;
          if (ACT) val = leaky_f(val, slope);
          if (OUT_BF16)
            ((unsigned short*)Cv)[(size_t)r * 256 + c] = f2bf(val);
          else
            ((float*)Cv)[(size_t)r * 256 + c] = val;
        }
      }
    }
  }
}

// ---- shared 64x256 GEMM body for the fused kernels. Block = 64 rows x 256
// cols, 4 waves (wave w -> cols w*64..w*64+63, all 64 rows). BK=64.
template <int A_BF16>
__device__ __forceinline__ void gemm_body_64x256(
    const void* __restrict__ Av, const unsigned short* __restrict__ B,
    int row0, int n_rows, int K, short As[64][72], short Bs[256][72],
    f32x4 acc[4][4]) {
  int t = threadIdx.x;
  int wave = t >> 6, lane = t & 63;
  int m16 = lane & 15, quad = lane >> 4;
  int wc = wave * 64;
  for (int k0 = 0; k0 < K; k0 += 64) {
    if (A_BF16) {
      const unsigned short* A = (const unsigned short*)Av;
#pragma unroll
      for (int p = 0; p < 2; ++p) {
        int e = (p * 256 + t) * 8;
        int row = e >> 6, k = e & 63;
        int ar = row0 + row; if (ar > n_rows - 1) ar = n_rows - 1;
        uint4 q = *(const uint4*)(A + (size_t)ar * K + k0 + k);
        *(uint4*)&As[row][k] = q;
      }
    } else {
      const float* A = (const float*)Av;
#pragma unroll
      for (int p = 0; p < 4; ++p) {
        int e = (p * 256 + t) * 4;
        int row = e >> 6, k = e & 63;
        int ar = row0 + row; if (ar > n_rows - 1) ar = n_rows - 1;
        float4 q = *(const float4*)(A + (size_t)ar * K + k0 + k);
        unsigned int lo = (unsigned int)f2bf(q.x) | ((unsigned int)f2bf(q.y) << 16);
        unsigned int hi = (unsigned int)f2bf(q.z) | ((unsigned int)f2bf(q.w) << 16);
        *(uint2*)&As[row][k] = make_uint2(lo, hi);
      }
    }
#pragma unroll
    for (int p = 0; p < 8; ++p) {
      int e = (p * 256 + t) * 8;
      int nn = e >> 6, k = e & 63;
      uint4 q = *(const uint4*)(B + (size_t)nn * K + k0 + k);
      *(uint4*)&Bs[nn][k] = q;
    }
    __syncthreads();
#pragma unroll
    for (int ks = 0; ks < 64; ks += 32) {
      bf16x8 af[4], bf[4];
#pragma unroll
      for (int i = 0; i < 4; ++i)
        af[i] = *(const bf16x8*)&As[i * 16 + m16][ks + quad * 8];
#pragma unroll
      for (int j = 0; j < 4; ++j)
        bf[j] = *(const bf16x8*)&Bs[wc + j * 16 + m16][ks + quad * 8];
#pragma unroll
      for (int i = 0; i < 4; ++i)
#pragma unroll
        for (int j = 0; j < 4; ++j)
          acc[i][j] = __builtin_amdgcn_mfma_f32_16x16x32_bf16(af[i], bf[j], acc[i][j], 0, 0, 0);
    }
    __syncthreads();
  }
}

// ---- GEMM1 fused with row softmax: z1 = leaky(xloc@fc^T+b, 0.01);
// sa = softmax(z1); x2b = bf16(leaky(xloc*sa, 0.2)). A = xloc fp32.
__global__ __launch_bounds__(256) void gemm_sm(
    const float* __restrict__ A, const unsigned short* __restrict__ B,
    const float* __restrict__ bias, unsigned short* __restrict__ x2b, int n_rows) {
  __shared__ short As[64][72];
  __shared__ short Bs[256][72];
  __shared__ float red[4][64];
  __shared__ float rowv[64];
  int t = threadIdx.x;
  int wave = t >> 6, lane = t & 63;
  int m16 = lane & 15, quad = lane >> 4;
  int wc = wave * 64;
  int row0 = blockIdx.x * 64;
  f32x4 acc[4][4];
#pragma unroll
  for (int i = 0; i < 4; ++i)
#pragma unroll
    for (int j = 0; j < 4; ++j) acc[i][j] = (f32x4){0.f, 0.f, 0.f, 0.f};
  gemm_body_64x256<0>(A, B, row0, n_rows, 256, As, Bs, acc);

  float bv[4];
#pragma unroll
  for (int j = 0; j < 4; ++j) bv[j] = bias[wc + j * 16 + m16];
#pragma unroll
  for (int i = 0; i < 4; ++i)
#pragma unroll
    for (int j = 0; j < 4; ++j)
#pragma unroll
      for (int v = 0; v < 4; ++v)
        acc[i][j][v] = leaky_f(acc[i][j][v] + bv[j], 0.01f);

  // round 1: row max
  float M[4][4];
#pragma unroll
  for (int i = 0; i < 4; ++i)
#pragma unroll
    for (int v = 0; v < 4; ++v) {
      float m = fmaxf(fmaxf(acc[i][0][v], acc[i][1][v]), fmaxf(acc[i][2][v], acc[i][3][v]));
      M[i][v] = red16_max(m);
    }
  if (m16 == 0)
#pragma unroll
    for (int i = 0; i < 4; ++i)
#pragma unroll
      for (int v = 0; v < 4; ++v) red[wave][i * 16 + quad * 4 + v] = M[i][v];
  __syncthreads();
  if (t < 64) rowv[t] = fmaxf(fmaxf(red[0][t], red[1][t]), fmaxf(red[2][t], red[3][t]));
  __syncthreads();
#pragma unroll
  for (int i = 0; i < 4; ++i)
#pragma unroll
    for (int v = 0; v < 4; ++v) M[i][v] = rowv[i * 16 + quad * 4 + v];
  __syncthreads();

  // round 2: exp + row sum
  float S[4][4];
#pragma unroll
  for (int i = 0; i < 4; ++i)
#pragma unroll
    for (int v = 0; v < 4; ++v) {
#pragma unroll
      for (int j = 0; j < 4; ++j) acc[i][j][v] = __expf(acc[i][j][v] - M[i][v]);
      float s = acc[i][0][v] + acc[i][1][v] + acc[i][2][v] + acc[i][3][v];
      S[i][v] = red16_sum(s);
    }
  if (m16 == 0)
#pragma unroll
    for (int i = 0; i < 4; ++i)
#pragma unroll
      for (int v = 0; v < 4; ++v) red[wave][i * 16 + quad * 4 + v] = S[i][v];
  __syncthreads();
  if (t < 64) rowv[t] = red[0][t] + red[1][t] + red[2][t] + red[3][t];
  __syncthreads();

  // x2 = leaky(xloc * e * inv, 0.2) -> bf16
#pragma unroll
  for (int i = 0; i < 4; ++i)
#pragma unroll
    for (int v = 0; v < 4; ++v) {
      int r = row0 + i * 16 + quad * 4 + v;
      float inv = 1.f / rowv[i * 16 + quad * 4 + v];
      if (r < n_rows) {
#pragma unroll
        for (int j = 0; j < 4; ++j) {
          int c = wc + j * 16 + m16;
          float xv = A[(size_t)r * 256 + c];
          x2b[(size_t)r * 256 + c] = f2bf(leaky_f(xv * acc[i][j][v] * inv, 0.2f));
        }
      }
    }
}

// ---- GEMM2 fused with LayerNorm + L2 norm + gate: x3 = x2@fc^T+b; LN;
// L2 normalize; gate logit -> egate. A = x2b bf16; out = xloc fp32.
__global__ __launch_bounds__(256) void gemm_ln(
    const unsigned short* __restrict__ A, const unsigned short* __restrict__ B,
    const float* __restrict__ bias, const float* __restrict__ ln_w,
    const float* __restrict__ ln_b, const float* __restrict__ gate_w,
    const float* __restrict__ gate_b, float* __restrict__ Cout,
    float* __restrict__ egate, int n_rows) {
  __shared__ short As[64][72];
  __shared__ short Bs[256][72];
  __shared__ float red[4][64];
  __shared__ float rowv[64];
  int t = threadIdx.x;
  int wave = t >> 6, lane = t & 63;
  int m16 = lane & 15, quad = lane >> 4;
  int wc = wave * 64;
  int row0 = blockIdx.x * 64;
  f32x4 acc[4][4];
#pragma unroll
  for (int i = 0; i < 4; ++i)
#pragma unroll
    for (int j = 0; j < 4; ++j) acc[i][j] = (f32x4){0.f, 0.f, 0.f, 0.f};
  gemm_body_64x256<1>(A, B, row0, n_rows, 256, As, Bs, acc);

  float bv[4], lw[4], lb[4], gw[4];
#pragma unroll
  for (int j = 0; j < 4; ++j) {
    int c = wc + j * 16 + m16;
    bv[j] = bias[c]; lw[j] = ln_w[c]; lb[j] = ln_b[c]; gw[j] = gate_w[c];
  }
#pragma unroll
  for (int i = 0; i < 4; ++i)
#pragma unroll
    for (int j = 0; j < 4; ++j)
#pragma unroll
      for (int v = 0; v < 4; ++v) acc[i][j][v] += bv[j];

  // round 1: mean
  float MU[4][4];
#pragma unroll
  for (int i = 0; i < 4; ++i)
#pragma unroll
    for (int v = 0; v < 4; ++v)
      MU[i][v] = red16_sum(acc[i][0][v] + acc[i][1][v] + acc[i][2][v] + acc[i][3][v]);
  if (m16 == 0)
#pragma unroll
    for (int i = 0; i < 4; ++i)
#pragma unroll
      for (int v = 0; v < 4; ++v) red[wave][i * 16 + quad * 4 + v] = MU[i][v];
  __syncthreads();
  if (t < 64) rowv[t] = (red[0][t] + red[1][t] + red[2][t] + red[3][t]) * (1.f / 256.f);
  __syncthreads();
#pragma unroll
  for (int i = 0; i < 4; ++i)
#pragma unroll
    for (int v = 0; v < 4; ++v) MU[i][v] = rowv[i * 16 + quad * 4 + v];
  __syncthreads();
#pragma unroll
  for (int i = 0; i < 4; ++i)
#pragma unroll
    for (int j = 0; j < 4; ++j)
#pragma unroll
      for (int v = 0; v < 4; ++v) acc[i][j][v] -= MU[i][v];

  // round 2: variance -> rstd
  float RS[4][4];
#pragma unroll
  for (int i = 0; i < 4; ++i)
#pragma unroll
    for (int v = 0; v < 4; ++v) {
      float q = acc[i][0][v] * acc[i][0][v] + acc[i][1][v] * acc[i][1][v] +
                acc[i][2][v] * acc[i][2][v] + acc[i][3][v] * acc[i][3][v];
      RS[i][v] = red16_sum(q);
    }
  if (m16 == 0)
#pragma unroll
    for (int i = 0; i < 4; ++i)
#pragma unroll
      for (int v = 0; v < 4; ++v) red[wave][i * 16 + quad * 4 + v] = RS[i][v];
  __syncthreads();
  if (t < 64) rowv[t] = rsqrtf(red[0][t] + red[1][t] + red[2][t] + red[3][t]) * 0.f +
                        rsqrtf((red[0][t] + red[1][t] + red[2][t] + red[3][t]) * (1.f / 256.f) + 1e-5f);
  __syncthreads();
#pragma unroll
  for (int i = 0; i < 4; ++i)
#pragma unroll
    for (int v = 0; v < 4; ++v) RS[i][v] = rowv[i * 16 + quad * 4 + v];
  __syncthreads();
  // y = c*rstd*lw + lb
#pragma unroll
  for (int i = 0; i < 4; ++i)
#pragma unroll
    for (int j = 0; j < 4; ++j)
#pragma unroll
      for (int v = 0; v < 4; ++v)
        acc[i][j][v] = acc[i][j][v] * RS[i][v] * lw[j] + lb[j];

  // round 3: L2 norm
  float NV[4][4];
#pragma unroll
  for (int i = 0; i < 4; ++i)
#pragma unroll
    for (int v = 0; v < 4; ++v) {
      float q = acc[i][0][v] * acc[i][0][v] + acc[i][1][v] * acc[i][1][v] +
                acc[i][2][v] * acc[i][2][v] + acc[i][3][v] * acc[i][3][v];
      NV[i][v] = red16_sum(q);
    }
  if (m16 == 0)
#pragma unroll
    for (int i = 0; i < 4; ++i)
#pragma unroll
      for (int v = 0; v < 4; ++v) red[wave][i * 16 + quad * 4 + v] = NV[i][v];
  __syncthreads();
  if (t < 64) rowv[t] = 1.f / fmaxf(sqrtf(red[0][t] + red[1][t] + red[2][t] + red[3][t]), 1e-12f);
  __syncthreads();
#pragma unroll
  for (int i = 0; i < 4; ++i)
#pragma unroll
    for (int v = 0; v < 4; ++v) NV[i][v] = rowv[i * 16 + quad * 4 + v];
  __syncthreads();
#pragma unroll
  for (int i = 0; i < 4; ++i)
#pragma unroll
    for (int j = 0; j < 4; ++j)
#pragma unroll
      for (int v = 0; v < 4; ++v) acc[i][j][v] *= NV[i][v];

  // round 4: gate logit -> egate (no broadcast-back needed)
  float GP[4][4];
#pragma unroll
  for (int i = 0; i < 4; ++i)
#pragma unroll
    for (int v = 0; v < 4; ++v) {
      float g = acc[i][0][v] * gw[0] + acc[i][1][v] * gw[1] +
                acc[i][2][v] * gw[2] + acc[i][3][v] * gw[3];
      GP[i][v] = red16_sum(g);
    }
  if (m16 == 0)
#pragma unroll
    for (int i = 0; i < 4; ++i)
#pragma unroll
      for (int v = 0; v < 4; ++v) red[wave][i * 16 + quad * 4 + v] = GP[i][v];
  __syncthreads();
  if (t < 64 && row0 + t < n_rows) {
    float gp = red[0][t] + red[1][t] + red[2][t] + red[3][t];
    egate[row0 + t] = __expf(gp + gate_b[0]);  // |gp| <= ~0.8, safe
  }
  // store y
#pragma unroll
  for (int i = 0; i < 4; ++i)
#pragma unroll
    for (int v = 0; v < 4; ++v) {
      int r = row0 + i * 16 + quad * 4 + v;
      if (r < n_rows) {
#pragma unroll
        for (int j = 0; j < 4; ++j)
          Cout[(size_t)r * 256 + wc + j * 16 + m16] = acc[i][j][v];
      }
    }
}

// ---- alpha from bf16 xp
__global__ void alpha_kernel(const unsigned short* __restrict__ xpb,
                             const float4* __restrict__ as4, const float4* __restrict__ ad4,
                             float* __restrict__ alpha_src, float* __restrict__ alpha_dst,
                             int n_nodes) {
  int i = blockIdx.x * 256 + threadIdx.x;
  if (i >= n_nodes * 8) return;
  int n = i >> 3, h = i & 7;
  const ushort4* xr = (const ushort4*)(xpb + (size_t)n * 256 + h * 32);
  float s = 0.f, d = 0.f;
#pragma unroll
  for (int j = 0; j < 8; ++j) {
    ushort4 q = xr[j];
    float4 a = as4[h * 8 + j];
    float4 b = ad4[h * 8 + j];
    float vx = bf2f(q.x), vy = bf2f(q.y), vz = bf2f(q.z), vw = bf2f(q.w);
    s += vx * a.x + vy * a.y + vz * a.z + vw * a.w;
    d += vx * b.x + vy * b.y + vz * b.z + vw * b.w;
  }
  alpha_src[i] = s;
  alpha_dst[i] = d;
}

// ---- CSR build
__global__ void hist_kernel(const int* __restrict__ dst, int* __restrict__ deg, int e) {
  int i = blockIdx.x * 256 + threadIdx.x;
  if (i < e) atomicAdd(&deg[dst[i]], 1);
}

__global__ __launch_bounds__(1024) void scan_kernel(const int* __restrict__ deg,
                                                    int* __restrict__ offsets,
                                                    int* __restrict__ curs, int n) {
  __shared__ int wsum[16];
  __shared__ int carry_s;
  int t = threadIdx.x, lane = t & 63, wv = t >> 6;
  if (t == 0) { carry_s = 0; offsets[0] = 0; }
  __syncthreads();
  for (int base = 0; base < n; base += 4096) {
    int i0 = base + t * 4;
    int4 v = make_int4(0, 0, 0, 0);
    if (i0 + 3 < n) v = *(const int4*)(deg + i0);
    else {
      if (i0 < n) v.x = deg[i0];
      if (i0 + 1 < n) v.y = deg[i0 + 1];
      if (i0 + 2 < n) v.z = deg[i0 + 2];
    }
    int p1 = v.x, p2 = p1 + v.y, p3 = p2 + v.z, p4 = p3 + v.w;
    int s = p4;
#pragma unroll
    for (int d = 1; d < 64; d <<= 1) {
      int u = __shfl_up(s, d);
      if (lane >= d) s += u;
    }
    if (lane == 63) wsum[wv] = s;
    __syncthreads();
    int woff = 0, total = 0;
#pragma unroll
    for (int k = 0; k < 16; ++k) {
      int wsk = wsum[k];
      woff += (k < wv) ? wsk : 0;
      total += wsk;
    }
    int carry = carry_s;
    int excl = carry + woff + s - p4;
    if (i0 < n)     { offsets[i0 + 1] = excl + p1; curs[i0]     = excl; }
    if (i0 + 1 < n) { offsets[i0 + 2] = excl + p2; curs[i0 + 1] = excl + p1; }
    if (i0 + 2 < n) { offsets[i0 + 3] = excl + p3; curs[i0 + 2] = excl + p2; }
    if (i0 + 3 < n) { offsets[i0 + 4] = excl + p4; curs[i0 + 3] = excl + p3; }
    __syncthreads();
    if (t == 0) carry_s = carry + total;
    __syncthreads();
  }
}

// ---- scatter + per-edge per-head softmax weights (pexp)
__global__ void scatter_kernel(const int* __restrict__ src, const int* __restrict__ dst,
                               int* __restrict__ cursor, const float* __restrict__ asrc,
                               const float* __restrict__ adst, int* __restrict__ ssrc,
                               float* __restrict__ pexp, int e) {
  int i = blockIdx.x * 256 + threadIdx.x;
  if (i < e) {
    int s = src[i], d = dst[i];
    int p = atomicAdd(&cursor[d], 1);
    ssrc[p] = s;
    float4 as0 = *(const float4*)(asrc + (size_t)s * 8);
    float4 as1 = *(const float4*)(asrc + (size_t)s * 8 + 4);
    float4 ad0 = *(const float4*)(adst + (size_t)d * 8);
    float4 ad1 = *(const float4*)(adst + (size_t)d * 8 + 4);
    float4 w0, w1;
    w0.x = __expf(leaky_f(as0.x + ad0.x, 0.2f));
    w0.y = __expf(leaky_f(as0.y + ad0.y, 0.2f));
    w0.z = __expf(leaky_f(as0.z + ad0.z, 0.2f));
    w0.w = __expf(leaky_f(as0.w + ad0.w, 0.2f));
    w1.x = __expf(leaky_f(as1.x + ad1.x, 0.2f));
    w1.y = __expf(leaky_f(as1.y + ad1.y, 0.2f));
    w1.z = __expf(leaky_f(as1.z + ad1.z, 0.2f));
    w1.w = __expf(leaky_f(as1.w + ad1.w, 0.2f));
    *(float4*)(pexp + (size_t)p * 8) = w0;
    *(float4*)(pexp + (size_t)p * 8 + 4) = w1;
  }
}

// ---- edge aggregation: gather + fma only (weights precomputed in scatter).
__global__ __launch_bounds__(256) void agg_kernel(
    const unsigned short* __restrict__ xpb, const float* __restrict__ asrc,
    const float* __restrict__ adst, const int* __restrict__ offsets,
    const int* __restrict__ ssrc, const float* __restrict__ pexp,
    const float4* __restrict__ conv_b4, float4* __restrict__ xloc4, int n_nodes) {
  int lane = threadIdx.x & 63, w = threadIdx.x >> 6;
  int n = blockIdx.x * 4 + w;
  if (n >= n_nodes) return;
  int h = lane >> 3;
  // self loop
  float p = __expf(leaky_f(asrc[n * 8 + h] + adst[n * 8 + h], 0.2f));
  ushort4 xq = ((const ushort4*)(xpb + (size_t)n * 256))[lane];
  float4 acc;
  acc.x = p * bf2f(xq.x); acc.y = p * bf2f(xq.y);
  acc.z = p * bf2f(xq.z); acc.w = p * bf2f(xq.w);
  float ssum = p;
  int beg = offsets[n], end = offsets[n + 1];
  int j = beg;
  for (; j + 8 <= end; j += 8) {
    int sv[8];
#pragma unroll
    for (int u = 0; u < 8; ++u) sv[u] = ssrc[j + u];
    float pu[8];
#pragma unroll
    for (int u = 0; u < 8; ++u) pu[u] = pexp[(size_t)(j + u) * 8 + h];
    ushort4 q[8];
#pragma unroll
    for (int u = 0; u < 8; ++u) q[u] = ((const ushort4*)(xpb + (size_t)sv[u] * 256))[lane];
#pragma unroll
    for (int u = 0; u < 8; ++u) {
      acc.x += pu[u] * bf2f(q[u].x); acc.y += pu[u] * bf2f(q[u].y);
      acc.z += pu[u] * bf2f(q[u].z); acc.w += pu[u] * bf2f(q[u].w);
      ssum += pu[u];
    }
  }
  for (; j + 4 <= end; j += 4) {
    int sv0 = ssrc[j], sv1 = ssrc[j + 1], sv2 = ssrc[j + 2], sv3 = ssrc[j + 3];
    float p0 = pexp[(size_t)j * 8 + h];
    float p1 = pexp[(size_t)(j + 1) * 8 + h];
    float p2 = pexp[(size_t)(j + 2) * 8 + h];
    float p3 = pexp[(size_t)(j + 3) * 8 + h];
    ushort4 q0 = ((const ushort4*)(xpb + (size_t)sv0 * 256))[lane];
    ushort4 q1 = ((const ushort4*)(xpb + (size_t)sv1 * 256))[lane];
    ushort4 q2 = ((const ushort4*)(xpb + (size_t)sv2 * 256))[lane];
    ushort4 q3 = ((const ushort4*)(xpb + (size_t)sv3 * 256))[lane];
    acc.x += p0 * bf2f(q0.x); acc.y += p0 * bf2f(q0.y);
    acc.z += p0 * bf2f(q0.z); acc.w += p0 * bf2f(q0.w);
    acc.x += p1 * bf2f(q1.x); acc.y += p1 * bf2f(q1.y);
    acc.z += p1 * bf2f(q1.z); acc.w += p1 * bf2f(q1.w);
    acc.x += p2 * bf2f(q2.x); acc.y += p2 * bf2f(q2.y);
    acc.z += p2 * bf2f(q2.z); acc.w += p2 * bf2f(q2.w);
    acc.x += p3 * bf2f(q3.x); acc.y += p3 * bf2f(q3.y);
    acc.z += p3 * bf2f(q3.z); acc.w += p3 * bf2f(q3.w);
    ssum += p0 + p1 + p2 + p3;
  }
  for (; j < end; ++j) {
    int sv = ssrc[j];
    float p1 = pexp[(size_t)j * 8 + h];
    ushort4 q = ((const ushort4*)(xpb + (size_t)sv * 256))[lane];
    acc.x += p1 * bf2f(q.x); acc.y += p1 * bf2f(q.y);
    acc.z += p1 * bf2f(q.z); acc.w += p1 * bf2f(q.w);
    ssum += p1;
  }
  float inv = 1.f / (ssum + 1e-16f);
  float4 b = conv_b4[lane];
  float4 o;
  o.x = acc.x * inv + b.x; o.y = acc.y * inv + b.y;
  o.z = acc.z * inv + b.z; o.w = acc.w * inv + b.w;
  xloc4[(size_t)n * 64 + lane] = o;
}

// ---- pooling + Ssum: per-block partials, one atomic per block (512 blocks)
__global__ __launch_bounds__(256) void pool_kernel(const float* __restrict__ xloc,
                                                   const float* __restrict__ egate,
                                                   float* __restrict__ xg,
                                                   float* __restrict__ Ssum, int n) {
  int c = threadIdx.x;
  int rpb = (n + (int)gridDim.x - 1) / (int)gridDim.x;
  int r0 = blockIdx.x * rpb;
  int r1 = r0 + rpb; if (r1 > n) r1 = n;
  float acc = 0.f, gs = 0.f;
  for (int r = r0; r < r1; ++r) {
    float g = egate[r];
    acc += g * xloc[(size_t)r * 256 + c];
    gs += g;
  }
  atomicAdd(&xg[c], acc);
  if (c == 0) atomicAdd(Ssum, gs);
}

__global__ __launch_bounds__(256) void gfc_kernel(const float* __restrict__ xg,
                                                  const float* __restrict__ S,
                                                  const float* __restrict__ gfcT,
                                                  const float* __restrict__ gfc_b,
                                                  float* __restrict__ ga) {
  __shared__ float xs[256];
  __shared__ float red[256];
  int t = threadIdx.x;
  float invS = 1.f / (S[0] + 1e-16f);
  xs[t] = xg[t] * invS;
  __syncthreads();
  float acc = gfc_b[t];
  for (int i = 0; i < 256; ++i) acc += xs[i] * gfcT[i * 256 + t];
  acc = fmaxf(acc, 0.f);
  red[t] = acc;
  __syncthreads();
  for (int s = 128; s > 0; s >>= 1) {
    if (t < s) red[t] = fmaxf(red[t], red[t + s]);
    __syncthreads();
  }
  float m = red[0];
  __syncthreads();
  float e = __expf(acc - m);
  red[t] = e;
  __syncthreads();
  for (int s = 128; s > 0; s >>= 1) {
    if (t < s) red[t] += red[t + s];
    __syncthreads();
  }
  ga[t] = e / red[0];
}

__global__ void out_kernel(const float4* __restrict__ xloc4, const float4* __restrict__ ga4,
                           float4* __restrict__ out4, int total4) {
  int i = blockIdx.x * 256 + threadIdx.x;
  if (i >= total4) return;
  float4 v = xloc4[i];
  float4 g = ga4[i & 63];
  v.x *= g.x; v.y *= g.y; v.z *= g.z; v.w *= g.w;
  out4[i] = v;
}

extern "C" void kernel_launch(void* const* d_in, const int* in_sizes, int n_in,
                              void* d_out, int out_size, void* d_ws, size_t ws_size,
                              hipStream_t stream) {
  const float* x      = (const float*)d_in[0];
  const int* edge_idx = (const int*)d_in[1];
  const float* W      = (const float*)d_in[4];
  const float* a_src  = (const float*)d_in[5];
  const float* a_dst  = (const float*)d_in[6];
  const float* conv_b = (const float*)d_in[7];
  const float* fc_w   = (const float*)d_in[8];
  const float* fc_b   = (const float*)d_in[9];
  const float* ln_w   = (const float*)d_in[10];
  const float* ln_b   = (const float*)d_in[11];
  const float* gate_w = (const float*)d_in[12];
  const float* gate_b = (const float*)d_in[13];
  const float* gfc_w  = (const float*)d_in[14];
  const float* gfc_b  = (const float*)d_in[15];
  (void)n_in; (void)out_size; (void)ws_size;

  int N = in_sizes[0] / 128;
  int E = in_sizes[1] / 2;
  const int* src = edge_idx;
  const int* dst = edge_idx + E;

  char* p = (char*)d_ws;
  auto alloc = [&](size_t bytes) -> char* {
    char* r = p;
    p += (bytes + 255) & ~(size_t)255;
    return r;
  };
  float*          xloc = (float*)alloc((size_t)N * 256 * 4);          // conv out / final x
  unsigned short* xpb  = (unsigned short*)alloc((size_t)N * 256 * 2); // bf16 xp
  unsigned short* x2b  = (unsigned short*)alloc((size_t)N * 256 * 2); // bf16 x2
  float* asrc  = (float*)alloc((size_t)N * 8 * 4);
  float* adst  = (float*)alloc((size_t)N * 8 * 4);
  unsigned short* Wb   = (unsigned short*)alloc(256 * 128 * 2);
  unsigned short* fcB  = (unsigned short*)alloc(256 * 256 * 2);
  float* gfcT  = (float*)alloc(256 * 256 * 4);
  float* egate = (float*)alloc((size_t)N * 4);
  int*   deg   = (int*)alloc((size_t)N * 4);
  int*   offs  = (int*)alloc((size_t)(N + 1) * 4);
  int*   curs  = (int*)alloc((size_t)N * 4);
  int*   ssrc  = (int*)alloc((size_t)E * 4);
  float* pexp  = (float*)alloc((size_t)E * 8 * 4);
  float* Ssum  = (float*)alloc(256);
  float* xg    = (float*)alloc(1024);
  float* ga    = (float*)alloc(1024);

  int nb = (N + 255) / 256;
  int eb = (E + 255) / 256;
  dim3 mgrid((N + 127) / 128, 2);
  int fgrid = (N + 63) / 64;

  repack_kernel<<<(256 * 128 + 2 * 256 * 256 + 255) / 256, 256, 0, stream>>>(
      W, fc_w, gfc_w, Wb, fcB, gfcT);
  zero_kernel<<<nb, 256, 0, stream>>>(deg, xg, Ssum, N);
  // xp(bf16) = x @ W
  mfma_gemm<0, 1, 0><<<mgrid, 256, 0, stream>>>(x, Wb, nullptr, xpb, N, 128, 0.f);
  alpha_kernel<<<(N * 8 + 255) / 256, 256, 0, stream>>>(
      xpb, (const float4*)a_src, (const float4*)a_dst, asrc, adst, N);
  hist_kernel<<<eb, 256, 0, stream>>>(dst, deg, E);
  scan_kernel<<<1, 1024, 0, stream>>>(deg, offs, curs, N);
  scatter_kernel<<<eb, 256, 0, stream>>>(src, dst, curs, asrc, adst, ssrc, pexp, E);
  agg_kernel<<<(N + 3) / 4, 256, 0, stream>>>(
      xpb, asrc, adst, offs, ssrc, pexp, (const float4*)conv_b, (float4*)xloc, N);
  // fused: z1 -> softmax -> x2(bf16)
  gemm_sm<<<fgrid, 256, 0, stream>>>(xloc, fcB, fc_b, x2b, N);
  // fused: x3 -> LN -> L2 -> gate; writes xloc + egate
  gemm_ln<<<fgrid, 256, 0, stream>>>(x2b, fcB, fc_b, ln_w, ln_b, gate_w, gate_b,
                                     xloc, egate, N);
  pool_kernel<<<512, 256, 0, stream>>>(xloc, egate, xg, Ssum, N);
  gfc_kernel<<<1, 256, 0, stream>>>(xg, Ssum, gfcT, gfc_b, ga);
  out_kernel<<<(N * 64 + 255) / 256, 256, 0, stream>>>(
      (const float4*)xloc, (const float4*)ga, (float4*)d_out, N * 64);
}